// Round 7
// baseline (10724.717 us; speedup 1.0000x reference)
//
#include <hip/hip_runtime.h>
#include <hip/hip_bf16.h>

#define EE 256
#define SS 16
#define GG 32000
#define NSTEP 128
#define ROWS 4096
#define VSPLIT 8
#define NWG 256

// ---------- workspace layout (bytes) ----------
#define OFF_ZSF  0u                     // f32 zs 4096x256 = 4 MB
#define OFF_TAIL 4194304u
#define OFF_ZN   (OFF_TAIL + 0u)        // f32 32x256 = 32768   (recurrence phase)
#define OFF_DZ   (OFF_TAIL + 32768u)    // f32 32x256 = 32768
#define OFF_A2   (OFF_TAIL + 65536u)    // f32 32x16  = 2048
#define OFF_PS   (OFF_TAIL + 0u)        // f32 8x4096 = 131072  (vocab phase, overlaps)
#define OFF_PT   (OFF_TAIL + 131072u)   // f32 8x4096 = 131072
#define OFF_BAR  (OFF_TAIL + 262144u)   // int[1024]: flags[0..255], gen@[320], is64@[384]
#define WS_REQ   (OFF_TAIL + 266240u)   // 4,460,544 B (confirmed available in rounds 5/6)

__device__ __forceinline__ float wredf(float v){
    #pragma unroll
    for (int m = 1; m < 64; m <<= 1) v += __shfl_xor(v, m);
    return v;
}

__device__ __forceinline__ int idx_at(const int* __restrict__ p, int i, int is64){
    return is64 ? p[2*i] : p[i];
}

__global__ __launch_bounds__(256) void k_sentinel(float* __restrict__ outp, float val){
    int r = blockIdx.x * 256 + threadIdx.x;
    outp[r] = val;
}

// ---------------- prep: zero barrier state + detect index dtype ----------------
__global__ void k_prep(const int* __restrict__ zi, int* __restrict__ bar){
    int t = threadIdx.x;
    bar[t] = 0;
    bar[256 + t] = 0;
    __syncthreads();
    if (t == 0){
        bool odd_zero = true, even_ok = true;
        for (int i = 0; i < 16; ++i){
            int lo = zi[2*i], hi = zi[2*i+1];
            if (hi != 0) odd_zero = false;
            if (lo < 0 || lo >= 8192) even_ok = false;
        }
        bar[384] = (odd_zero && even_ok) ? 1 : 0;
    }
}

// ---------------- grid barrier (flag-array + generation, agent scope) ----------
__device__ __forceinline__ void gridbar(int* __restrict__ flags, int* __restrict__ genp, int g){
    __threadfence();                       // release: my prior writes -> agent visible
    __syncthreads();
    const int wg = blockIdx.x;
    const int t  = threadIdx.x;
    if (wg == 0){
        if (t > 0){                        // t in [1,255] waits for WG t
            while (__hip_atomic_load(&flags[t], __ATOMIC_RELAXED, __HIP_MEMORY_SCOPE_AGENT) < g)
                __builtin_amdgcn_s_sleep(2);
        }
        __syncthreads();
        if (t == 0)
            __hip_atomic_store(genp, g, __ATOMIC_RELAXED, __HIP_MEMORY_SCOPE_AGENT);
    } else {
        if (t == 0){
            __hip_atomic_store(&flags[wg], g, __ATOMIC_RELAXED, __HIP_MEMORY_SCOPE_AGENT);
            while (__hip_atomic_load(genp, __ATOMIC_RELAXED, __HIP_MEMORY_SCOPE_AGENT) < g)
                __builtin_amdgcn_s_sleep(2);
        }
    }
    __syncthreads();
    __threadfence();                       // acquire: drop stale cached data
}

// ---------------- fused recurrence: 128 steps, 2 phases/step ----------------
__global__ __launch_bounds__(256) void k_fused(const float* __restrict__ latent,
                                               const int* __restrict__ zi,
                                               const float* __restrict__ anchor_w,
                                               const float* __restrict__ anchor_b,
                                               const float* __restrict__ trans_w,
                                               const float* __restrict__ trans_b,
                                               float* __restrict__ znf,
                                               float* __restrict__ dzf,
                                               float* __restrict__ att2f,
                                               float* __restrict__ zsf,
                                               int* __restrict__ bar)
{
    const int wg = blockIdx.x, t = threadIdx.x;
    __shared__ float wl[16][260];     // persistent trans_w e-slice
    __shared__ float znl[32][260];    // per-step zn stage (phase1 scratch overlays row 0)
    __shared__ float red[8][33];
    __shared__ float l1s[16], l2s[16], rbuf[8];

    int* flags = bar;
    int* genp  = bar + 320;
    const int is64 = bar[384];

    const int e = wg;
    #pragma unroll
    for (int m = 0; m < 16; ++m)
        wl[m][t] = trans_w[((size_t)(m*EE + e)) * EE + t];

    const float* base = nullptr;
    float zn_reg = 0.f, em_reg = 0.f;
    if (wg < 32){
        int zb = idx_at(zi, wg, is64);
        base = latent + (size_t)zb * 8192;   // xk = base[0:4096]*100, xv = base[4096:]*100
    }
    __syncthreads();

    int gen = 0;
    for (int stp = 0; stp < NSTEP; ++stp){
        // ---- phase 1: per-batch norm + att + att2 + emit (WGs 0..31) ----
        if (wg < 32){
            const int b = wg;
            float zv = (stp == 0) ? base[t] : (zn_reg + em_reg + dzf[b*EE + t]);
            float s1 = wredf(zv), s2 = wredf(zv*zv);
            if ((t & 63) == 0){ rbuf[t>>6] = s1; rbuf[4+(t>>6)] = s2; }
            __syncthreads();
            float tot1 = rbuf[0]+rbuf[1]+rbuf[2]+rbuf[3];
            float tot2 = rbuf[4]+rbuf[5]+rbuf[6]+rbuf[7];
            float mean = tot1 * (1.0f/EE);
            float var  = (tot2 - (float)EE*mean*mean) * (1.0f/(EE-1));
            var = fmaxf(var, 0.f);
            float sc = 0.113f / (1e-5f + sqrtf(var));
            float zn = zv * sc;
            znl[0][t] = zn;
            znf[b*EE + t] = zn;
            zn_reg = zn;
            __syncthreads();

            int sidx = t >> 4, l16 = t & 15;
            const float* xks = base + sidx*EE;
            const float* aws = anchor_w + (size_t)sidx*EE;
            float p1 = 0.f, p2 = 0.f;
            #pragma unroll
            for (int c = 0; c < 16; ++c){
                int k = l16*16 + c;
                float z = znl[0][k];
                p1 += z * xks[k];
                p2 += z * aws[k];
            }
            #pragma unroll
            for (int m = 1; m < 16; m <<= 1){ p1 += __shfl_xor(p1, m); p2 += __shfl_xor(p2, m); }
            if (l16 == 0){ l1s[sidx] = p1 * 100.0f; l2s[sidx] = p2 + anchor_b[sidx]; }
            __syncthreads();

            float mx1 = -1e30f, mx2 = -1e30f;
            #pragma unroll
            for (int s = 0; s < 16; ++s){ mx1 = fmaxf(mx1, l1s[s]); mx2 = fmaxf(mx2, l2s[s]); }
            float att[16]; float sum1 = 0.f, sum2 = 0.f;
            #pragma unroll
            for (int s = 0; s < 16; ++s){
                att[s] = expf(l1s[s] - mx1); sum1 += att[s];
                sum2  += expf(l2s[s] - mx2);
            }
            float inv1 = 1.0f / sum1;
            if (t < 16) att2f[b*16 + t] = expf(l2s[t] - mx2) / sum2;

            const float* xvb = base + 4096;
            float em = 0.f;
            #pragma unroll
            for (int s = 0; s < 16; ++s) em += (att[s] * inv1) * xvb[s*EE + t];
            em *= 100.0f;
            em_reg = em;
            zsf[((size_t)b*NSTEP + stp)*EE + t] = em;
        }
        gen++; gridbar(flags, genp, gen);
        if (stp == NSTEP-1) break;

        // ---- phase 2: dz[b,e] for this WG's e-column (all 256 WGs) ----
        #pragma unroll
        for (int b = 0; b < 32; ++b) znl[b][t] = znf[b*EE + t];
        __syncthreads();
        {
            int b = t & 31, g = t >> 5;      // g in 0..7, m = {g, g+8}
            float acc0 = 0.f, acc1 = 0.f;
            #pragma unroll 4
            for (int k = 0; k < EE; k += 4){
                float4 z4 = *(const float4*)&znl[b][k];
                float4 w0 = *(const float4*)&wl[g][k];
                float4 w1 = *(const float4*)&wl[g+8][k];
                acc0 += z4.x*w0.x + z4.y*w0.y + z4.z*w0.z + z4.w*w0.w;
                acc1 += z4.x*w1.x + z4.y*w1.y + z4.z*w1.z + z4.w*w1.w;
            }
            float a0 = att2f[b*16 + g], a1 = att2f[b*16 + g + 8];
            red[g][b] = a0*(acc0 + trans_b[g*EE + e]) + a1*(acc1 + trans_b[(g+8)*EE + e]);
        }
        __syncthreads();
        if (t < 32){
            float dz = 0.f;
            #pragma unroll
            for (int gg = 0; gg < 8; ++gg) dz += red[gg][t];
            dzf[t*EE + e] = dz;
        }
        gen++; gridbar(flags, genp, gen);
    }
}

// ---------------- vocab: f32 VALU logits + streaming sumexp + target ----------
__global__ __launch_bounds__(256) void k_vocab_valu(const float* __restrict__ vw,
                                                    const float* __restrict__ vbias,
                                                    const float* __restrict__ zsf,
                                                    const int* __restrict__ y,
                                                    const int* __restrict__ flag,
                                                    float* __restrict__ pS,
                                                    float* __restrict__ pT)
{
    int rowgrp = blockIdx.x;
    int vs     = blockIdx.y;
    int t = threadIdx.x;

    __shared__ float zl[32][256];
    __shared__ int   yl[32];
    __shared__ float rs[4][32], rt[4][32];

    #pragma unroll
    for (int r = 0; r < 32; ++r) zl[r][t] = zsf[(size_t)(rowgrp*32 + r) * EE + t];
    if (t < 32) yl[t] = idx_at(y, rowgrp*32 + t, flag[0]);
    __syncthreads();

    float sums[32], targ[32];
    #pragma unroll
    for (int r = 0; r < 32; ++r){ sums[r] = 0.f; targ[r] = 0.f; }

    for (int p = t; p < 2000; p += 256){
        int n0 = vs*4000 + 2*p, n1 = n0 + 1;
        const float* w0 = vw + (size_t)n0 * EE;
        const float* w1 = w0 + EE;
        float acc0[32], acc1[32];
        #pragma unroll
        for (int r = 0; r < 32; ++r){ acc0[r] = 0.f; acc1[r] = 0.f; }
        for (int k = 0; k < EE; k += 4){
            float4 a = *(const float4*)&w0[k];
            float4 c = *(const float4*)&w1[k];
            #pragma unroll
            for (int r = 0; r < 32; ++r){
                float4 z = *(const float4*)&zl[r][k];
                acc0[r] += z.x*a.x + z.y*a.y + z.z*a.z + z.w*a.w;
                acc1[r] += z.x*c.x + z.y*c.y + z.z*c.z + z.w*c.w;
            }
        }
        float b0 = vbias[n0], b1 = vbias[n1];
        #pragma unroll
        for (int r = 0; r < 32; ++r){
            float v0 = acc0[r] + b0, v1 = acc1[r] + b1;
            sums[r] += expf(v0) + expf(v1);
            if (n0 == yl[r]) targ[r] += v0;
            if (n1 == yl[r]) targ[r] += v1;
        }
    }

    int wv = t >> 6, ln = t & 63;
    #pragma unroll
    for (int r = 0; r < 32; ++r){
        float s = sums[r], g = targ[r];
        #pragma unroll
        for (int m = 1; m < 64; m <<= 1){ s += __shfl_xor(s, m); g += __shfl_xor(g, m); }
        if (ln == 0){ rs[wv][r] = s; rt[wv][r] = g; }
    }
    __syncthreads();
    if (t < 32){
        float s = rs[0][t] + rs[1][t] + rs[2][t] + rs[3][t];
        float g = rt[0][t] + rt[1][t] + rt[2][t] + rt[3][t];
        int r = rowgrp*32 + t;
        pS[(size_t)vs*ROWS + r] = s;
        pT[(size_t)vs*ROWS + r] = g;
    }
}

__global__ __launch_bounds__(256) void k_final(const float* __restrict__ pS,
                                               const float* __restrict__ pT,
                                               float* __restrict__ outp)
{
    int r = blockIdx.x * 256 + threadIdx.x;
    float s = 0.f, g = 0.f;
    #pragma unroll
    for (int i = 0; i < VSPLIT; ++i){ s += pS[(size_t)i*ROWS + r]; g += pT[(size_t)i*ROWS + r]; }
    outp[r] = g - logf(s);
}

extern "C" void kernel_launch(void* const* d_in, const int* in_sizes, int n_in,
                              void* d_out, int out_size, void* d_ws, size_t ws_size,
                              hipStream_t stream)
{
    (void)out_size;
    const float* latent   = (const float*)d_in[0];
    const float* trans_w  = (const float*)d_in[1];
    const float* trans_b  = (const float*)d_in[2];
    const float* anchor_w = (const float*)d_in[3];
    const float* anchor_b = (const float*)d_in[4];
    const float* vocab_w  = (const float*)d_in[5];
    const float* vocab_b  = (const float*)d_in[6];
    const int*   zi       = (const int*)d_in[7];
    const int*   y        = (const int*)d_in[8];

    float* outp = (float*)d_out;

    if (ws_size < (size_t)WS_REQ){ k_sentinel<<<16, 256, 0, stream>>>(outp, 2000.0f); return; }
    {
        bool ok = (n_in >= 9)
               && in_sizes[0] == 67108864 && in_sizes[1] == 1048576
               && in_sizes[2] == 4096     && in_sizes[3] == 4096
               && in_sizes[4] == 16       && in_sizes[5] == 8192000
               && in_sizes[6] == 32000
               && (in_sizes[7] == 32   || in_sizes[7] == 64)
               && (in_sizes[8] == 4096 || in_sizes[8] == 8192);
        if (!ok){ k_sentinel<<<16, 256, 0, stream>>>(outp, 2100.0f); return; }
    }

    char* ws = (char*)d_ws;
    float* zsf   = (float*)(ws + OFF_ZSF);
    float* znf   = (float*)(ws + OFF_ZN);
    float* dzf   = (float*)(ws + OFF_DZ);
    float* att2f = (float*)(ws + OFF_A2);
    float* pS    = (float*)(ws + OFF_PS);
    float* pT    = (float*)(ws + OFF_PT);
    int*   bar   = (int*)(ws + OFF_BAR);

    k_prep<<<1, 256, 0, stream>>>(zi, bar);

    {
        void* args[] = {(void*)&latent, (void*)&zi, (void*)&anchor_w, (void*)&anchor_b,
                        (void*)&trans_w, (void*)&trans_b, (void*)&znf, (void*)&dzf,
                        (void*)&att2f, (void*)&zsf, (void*)&bar};
        hipError_t err = hipLaunchCooperativeKernel((const void*)k_fused,
                                                    dim3(NWG), dim3(256), args, 0, stream);
        if (err != hipSuccess){
            // fallback: plain launch — 256 WGs on 256 CUs co-reside (LDS 51 KB -> >=1 WG/CU)
            k_fused<<<NWG, 256, 0, stream>>>(latent, zi, anchor_w, anchor_b,
                                             trans_w, trans_b, znf, dzf, att2f, zsf, bar);
        }
    }

    k_vocab_valu<<<dim3(128, VSPLIT), 256, 0, stream>>>(vocab_w, vocab_b, zsf, y,
                                                        bar + 384, pS, pT);
    k_final<<<16, 256, 0, stream>>>(pS, pT, outp);
}

// Round 8
// 9236.848 us; speedup vs baseline: 1.1611x; 1.1611x over previous
//
#include <hip/hip_runtime.h>

#define EE 256
#define GG 32000
#define NSTEP 128
#define ROWS 4096
#define VSPLIT 8

// ---------- workspace layout (bytes) ----------
#define OFF_ZSF  0u                     // f32 zs 4096x256 = 4 MB
#define OFF_PS   4194304u               // f32 8x4096 = 128 KB
#define OFF_PT   (OFF_PS + 131072u)     // 128 KB
#define OFF_FLAG (OFF_PT + 131072u)     // int flag
#define WS_REQ   (OFF_FLAG + 4096u)     // 4,460,544 B (confirmed available)

__device__ __forceinline__ float wredf(float v){
    #pragma unroll
    for (int m = 1; m < 64; m <<= 1) v += __shfl_xor(v, m);
    return v;
}

__global__ __launch_bounds__(256) void k_sentinel(float* __restrict__ outp, float val){
    int r = blockIdx.x * 256 + threadIdx.x;
    outp[r] = val;
}

// ---------------- prep: detect index dtype (int64 vs int32) ----------------
__global__ void k_prep(const int* __restrict__ zi, int* __restrict__ flag){
    if (threadIdx.x == 0 && blockIdx.x == 0){
        bool odd_zero = true, even_ok = true;
        for (int i = 0; i < 16; ++i){
            int lo = zi[2*i], hi = zi[2*i+1];
            if (hi != 0) odd_zero = false;
            if (lo < 0 || lo >= 8192) even_ok = false;
        }
        flag[0] = (odd_zero && even_ok) ? 1 : 0;
    }
}

// ---------------- fused recurrence: ONE WG PER BATCH, zero grid sync --------
__global__ __launch_bounds__(1024, 1) void k_rnn(const float* __restrict__ latent,
                                                 const int* __restrict__ zi,
                                                 const float* __restrict__ anchor_w,
                                                 const float* __restrict__ anchor_b,
                                                 const float* __restrict__ trans_w,
                                                 const float* __restrict__ trans_b,
                                                 float* __restrict__ zsf,
                                                 const int* __restrict__ flag)
{
    __shared__ float xk_l[16][260];   // latent[zb][0][s][:]   (raw, x100 folded into logits/emit)
    __shared__ float xv_l[16][260];   // latent[zb][1][s][:]
    __shared__ float aw_l[16][260];   // anchor_w
    __shared__ float tb_l[16][257];   // trans_b as [m][e]
    __shared__ float pd[16][260];     // per-wave phase-D partials
    __shared__ float zl[256];
    __shared__ float l1s[16], l2s[16], a2s[16], ab_l[16], rbuf[8];

    const int b = blockIdx.x, t = threadIdx.x;
    const int zb = flag[0] ? zi[2*b] : zi[b];
    const float* base = latent + (size_t)zb * 8192;

    for (int i = t; i < 4096; i += 1024){
        int s = i >> 8, c = i & 255;
        xk_l[s][c] = base[i];
        xv_l[s][c] = base[4096 + i];
        aw_l[s][c] = anchor_w[i];
        tb_l[s][c] = trans_b[i];
    }
    if (t < 16) ab_l[t] = anchor_b[t];
    __syncthreads();

    // phase-D roles: 16-lane k-slices, 16 m-groups, 4 e-quarters
    const int m16 = (t >> 4) & 15, l16 = t & 15, eh = t >> 8;   // eh in 0..3
    const float* wbase = trans_w + (size_t)m16 * EE * EE + l16 * 16;

    float zv = 0.f, zn_r = 0.f, em_r = 0.f;

    for (int stp = 0; stp < NSTEP; ++stp){
        // ---- z update + norm (threads 0..255; thread t owns z[t]) ----
        if (t < 256){
            if (stp == 0) zv = base[t];
            else {
                int q4 = (t >> 6) * 4;   // waves 4q..4q+3 wrote this e-quarter
                zv = zn_r + em_r + (pd[q4][t] + pd[q4+1][t] + pd[q4+2][t] + pd[q4+3][t]);
            }
            float s1 = wredf(zv), s2 = wredf(zv * zv);
            if ((t & 63) == 0){ rbuf[t>>6] = s1; rbuf[4 + (t>>6)] = s2; }
        }
        __syncthreads();
        if (t < 256){
            float tot1 = rbuf[0]+rbuf[1]+rbuf[2]+rbuf[3];
            float tot2 = rbuf[4]+rbuf[5]+rbuf[6]+rbuf[7];
            float mean = tot1 * (1.0f/EE);
            float var  = (tot2 - (float)EE*mean*mean) * (1.0f/(EE-1));
            var = fmaxf(var, 0.f);
            float sc = 0.113f / (1e-5f + sqrtf(var));
            zn_r = zv * sc;
            zl[t] = zn_r;
        }
        __syncthreads();
        // ---- logits ----
        if (t < 256){
            int sidx = t >> 4;
            float p1 = 0.f, p2 = 0.f;
            #pragma unroll
            for (int c = 0; c < 16; ++c){
                int k = l16*16 + c;
                float z = zl[k];
                p1 += z * xk_l[sidx][k];
                p2 += z * aw_l[sidx][k];
            }
            #pragma unroll
            for (int m = 1; m < 16; m <<= 1){ p1 += __shfl_xor(p1, m); p2 += __shfl_xor(p2, m); }
            if (l16 == 0){ l1s[sidx] = p1 * 100.0f; l2s[sidx] = p2 + ab_l[sidx]; }
        }
        __syncthreads();
        // ---- softmax + emit ----
        if (t < 256){
            float mx1 = -1e30f, mx2 = -1e30f;
            #pragma unroll
            for (int s = 0; s < 16; ++s){ mx1 = fmaxf(mx1, l1s[s]); mx2 = fmaxf(mx2, l2s[s]); }
            float att[16]; float sum1 = 0.f, sum2 = 0.f;
            #pragma unroll
            for (int s = 0; s < 16; ++s){
                att[s] = expf(l1s[s] - mx1); sum1 += att[s];
                sum2  += expf(l2s[s] - mx2);
            }
            float inv1 = 1.0f / sum1;
            if (t < 16) a2s[t] = expf(l2s[t] - mx2) / sum2;
            float em = 0.f;
            #pragma unroll
            for (int s = 0; s < 16; ++s) em += (att[s] * inv1) * xv_l[s][t];
            em *= 100.0f;
            em_r = em;
            zsf[((size_t)b * NSTEP + stp) * EE + t] = em;
        }
        __syncthreads();
        if (stp == NSTEP-1) break;

        // ---- phase D: dz-partials, all 1024 threads ----
        float zr[16];
        #pragma unroll
        for (int j = 0; j < 16; ++j) zr[j] = zl[l16*16 + j];
        const float a2m = a2s[m16];
        #pragma unroll 2
        for (int i = 0; i < 64; ++i){
            const int e = eh*64 + i;
            const float* wr = wbase + (size_t)e * EE;
            float4 w0 = *(const float4*)(wr);
            float4 w1 = *(const float4*)(wr + 4);
            float4 w2 = *(const float4*)(wr + 8);
            float4 w3 = *(const float4*)(wr + 12);
            float p = zr[0]*w0.x + zr[1]*w0.y + zr[2]*w0.z + zr[3]*w0.w
                    + zr[4]*w1.x + zr[5]*w1.y + zr[6]*w1.z + zr[7]*w1.w
                    + zr[8]*w2.x + zr[9]*w2.y + zr[10]*w2.z + zr[11]*w2.w
                    + zr[12]*w3.x + zr[13]*w3.y + zr[14]*w3.z + zr[15]*w3.w;
            p += __shfl_xor(p, 1); p += __shfl_xor(p, 2);
            p += __shfl_xor(p, 4); p += __shfl_xor(p, 8);
            float v = a2m * (p + tb_l[m16][e]);
            v += __shfl_xor(v, 16); v += __shfl_xor(v, 32);
            if ((t & 63) == 0) pd[t>>6][e] = v;
        }
        __syncthreads();
    }
}

// ---------------- vocab: f32 VALU logits + streaming sumexp + target ----------
__global__ __launch_bounds__(256) void k_vocab_valu(const float* __restrict__ vw,
                                                    const float* __restrict__ vbias,
                                                    const float* __restrict__ zsf,
                                                    const int* __restrict__ y,
                                                    const int* __restrict__ flag,
                                                    float* __restrict__ pS,
                                                    float* __restrict__ pT)
{
    int rowgrp = blockIdx.x;
    int vs     = blockIdx.y;
    int t = threadIdx.x;

    __shared__ float zl[32][256];
    __shared__ int   yl[32];
    __shared__ float rs[4][32], rt[4][32];

    #pragma unroll
    for (int r = 0; r < 32; ++r) zl[r][t] = zsf[(size_t)(rowgrp*32 + r) * EE + t];
    if (t < 32) yl[t] = flag[0] ? y[2*(rowgrp*32 + t)] : y[rowgrp*32 + t];
    __syncthreads();

    float sums[32], targ[32];
    #pragma unroll
    for (int r = 0; r < 32; ++r){ sums[r] = 0.f; targ[r] = 0.f; }

    for (int p = t; p < 2000; p += 256){
        int n0 = vs*4000 + 2*p, n1 = n0 + 1;
        const float* w0 = vw + (size_t)n0 * EE;
        const float* w1 = w0 + EE;
        float acc0[32], acc1[32];
        #pragma unroll
        for (int r = 0; r < 32; ++r){ acc0[r] = 0.f; acc1[r] = 0.f; }
        for (int k = 0; k < EE; k += 4){
            float4 a = *(const float4*)&w0[k];
            float4 c = *(const float4*)&w1[k];
            #pragma unroll
            for (int r = 0; r < 32; ++r){
                float4 z = *(const float4*)&zl[r][k];
                acc0[r] += z.x*a.x + z.y*a.y + z.z*a.z + z.w*a.w;
                acc1[r] += z.x*c.x + z.y*c.y + z.z*c.z + z.w*c.w;
            }
        }
        float b0 = vbias[n0], b1 = vbias[n1];
        #pragma unroll
        for (int r = 0; r < 32; ++r){
            float v0 = acc0[r] + b0, v1 = acc1[r] + b1;
            sums[r] += expf(v0) + expf(v1);
            if (n0 == yl[r]) targ[r] += v0;
            if (n1 == yl[r]) targ[r] += v1;
        }
    }

    int wv = t >> 6, ln = t & 63;
    #pragma unroll
    for (int r = 0; r < 32; ++r){
        float s = sums[r], g = targ[r];
        #pragma unroll
        for (int m = 1; m < 64; m <<= 1){ s += __shfl_xor(s, m); g += __shfl_xor(g, m); }
        if (ln == 0){ rs[wv][r] = s; rt[wv][r] = g; }
    }
    __syncthreads();
    if (t < 32){
        float s = rs[0][t] + rs[1][t] + rs[2][t] + rs[3][t];
        float g = rt[0][t] + rt[1][t] + rt[2][t] + rt[3][t];
        int r = rowgrp*32 + t;
        pS[(size_t)vs*ROWS + r] = s;
        pT[(size_t)vs*ROWS + r] = g;
    }
}

__global__ __launch_bounds__(256) void k_final(const float* __restrict__ pS,
                                               const float* __restrict__ pT,
                                               float* __restrict__ outp)
{
    int r = blockIdx.x * 256 + threadIdx.x;
    float s = 0.f, g = 0.f;
    #pragma unroll
    for (int i = 0; i < VSPLIT; ++i){ s += pS[(size_t)i*ROWS + r]; g += pT[(size_t)i*ROWS + r]; }
    outp[r] = g - logf(s);
}

extern "C" void kernel_launch(void* const* d_in, const int* in_sizes, int n_in,
                              void* d_out, int out_size, void* d_ws, size_t ws_size,
                              hipStream_t stream)
{
    (void)out_size;
    const float* latent   = (const float*)d_in[0];
    const float* trans_w  = (const float*)d_in[1];
    const float* trans_b  = (const float*)d_in[2];
    const float* anchor_w = (const float*)d_in[3];
    const float* anchor_b = (const float*)d_in[4];
    const float* vocab_w  = (const float*)d_in[5];
    const float* vocab_b  = (const float*)d_in[6];
    const int*   zi       = (const int*)d_in[7];
    const int*   y        = (const int*)d_in[8];

    float* outp = (float*)d_out;

    if (ws_size < (size_t)WS_REQ){ k_sentinel<<<16, 256, 0, stream>>>(outp, 2000.0f); return; }
    {
        bool ok = (n_in >= 9)
               && in_sizes[0] == 67108864 && in_sizes[1] == 1048576
               && in_sizes[2] == 4096     && in_sizes[3] == 4096
               && in_sizes[4] == 16       && in_sizes[5] == 8192000
               && in_sizes[6] == 32000
               && (in_sizes[7] == 32   || in_sizes[7] == 64)
               && (in_sizes[8] == 4096 || in_sizes[8] == 8192);
        if (!ok){ k_sentinel<<<16, 256, 0, stream>>>(outp, 2100.0f); return; }
    }

    char* ws = (char*)d_ws;
    float* zsf  = (float*)(ws + OFF_ZSF);
    float* pS   = (float*)(ws + OFF_PS);
    float* pT   = (float*)(ws + OFF_PT);
    int*   flag = (int*)(ws + OFF_FLAG);

    k_prep<<<1, 64, 0, stream>>>(zi, flag);

    k_rnn<<<32, 1024, 0, stream>>>(latent, zi, anchor_w, anchor_b,
                                   trans_w, trans_b, zsf, flag);

    k_vocab_valu<<<dim3(128, VSPLIT), 256, 0, stream>>>(vocab_w, vocab_b, zsf, y,
                                                        flag, pS, pT);
    k_final<<<16, 256, 0, stream>>>(pS, pT, outp);
}

// Round 10
// 3894.668 us; speedup vs baseline: 2.7537x; 2.3717x over previous
//
#include <hip/hip_runtime.h>

#define EE 256
#define GG 32000
#define NSTEP 128
#define ROWS 4096
#define VSPLIT 8
#define NWGR 64

// ---------- workspace layout (bytes) ----------
#define OFF_ZSF  0u                     // f32 zs 4096x256 = 4 MB
#define OFF_PD   4194304u               // 256 KB partials (recurrence) ...
#define OFF_PS   4194304u               // ... overlaid by vocab pS (128 KB)
#define OFF_PT   (OFF_PS + 131072u)     // vocab pT (128 KB)
#define OFF_ZN   (OFF_PD + 262144u)     // 32 KB
#define OFF_A2   (OFF_ZN + 32768u)      // 2 KB (padded)
#define OFF_BAR  (OFF_A2 + 4096u)       // 1 KB ints
#define WS_REQ   (OFF_BAR + 4096u)      // 4,497,408 <= confirmed 4,560,896

// bar int slots: flags[1..63], rel@128, dead@132, is64@136

__device__ __forceinline__ float wredf(float v){
    #pragma unroll
    for (int m = 1; m < 64; m <<= 1) v += __shfl_xor(v, m);
    return v;
}

__global__ __launch_bounds__(256) void k_sentinel(float* __restrict__ outp, float val){
    int r = blockIdx.x * 256 + threadIdx.x;
    outp[r] = val;
}

__global__ void k_prep(const int* __restrict__ zi, int* __restrict__ bar){
    int t = threadIdx.x;
    bar[t] = 0;            // zero flags/rel/dead (re-zeroed EVERY replay)
    __syncthreads();
    if (t == 0){
        bool odd_zero = true, even_ok = true;
        for (int i = 0; i < 16; ++i){
            int lo = zi[2*i], hi = zi[2*i+1];
            if (hi != 0) odd_zero = false;
            if (lo < 0 || lo >= 8192) even_ok = false;
        }
        bar[136] = (odd_zero && even_ok) ? 1 : 0;
    }
}

// ---- grid barrier: round-7-proven semantics (fence + atomic flags), 1 fence-thread/WG ----
__device__ __forceinline__ void gbar(int* __restrict__ bar, int gen){
    __syncthreads();   // drains this WG's vmem (stores are in L2)
    const int t = threadIdx.x, wg = blockIdx.x;
    if (wg == 0){
        if (t >= 1 && t < NWGR){
            int spins = 0;
            while (__hip_atomic_load(&bar[t], __ATOMIC_RELAXED, __HIP_MEMORY_SCOPE_AGENT) < gen){
                __builtin_amdgcn_s_sleep(2);
                if (++spins > 1000000){
                    __hip_atomic_store(&bar[132], 1, __ATOMIC_RELAXED, __HIP_MEMORY_SCOPE_AGENT);
                    break;
                }
                if ((spins & 2047) == 0 &&
                    __hip_atomic_load(&bar[132], __ATOMIC_RELAXED, __HIP_MEMORY_SCOPE_AGENT) != 0)
                    break;
            }
        }
        __syncthreads();
        if (t == 0){
            __threadfence();   // wb (release of WG0 data) + inv (acquire: flags seen => remote wb done)
            __hip_atomic_store(&bar[128], gen, __ATOMIC_RELAXED, __HIP_MEMORY_SCOPE_AGENT);
        }
        __syncthreads();
    } else {
        if (t == 0){
            __threadfence();   // release: write back this XCD-L2's dirty data to LLC
            __hip_atomic_store(&bar[wg], gen, __ATOMIC_RELAXED, __HIP_MEMORY_SCOPE_AGENT);
            int spins = 0;
            while (__hip_atomic_load(&bar[128], __ATOMIC_RELAXED, __HIP_MEMORY_SCOPE_AGENT) < gen){
                __builtin_amdgcn_s_sleep(2);
                if (++spins > 1000000){
                    __hip_atomic_store(&bar[132], 1, __ATOMIC_RELAXED, __HIP_MEMORY_SCOPE_AGENT);
                    break;
                }
                if ((spins & 2047) == 0 &&
                    __hip_atomic_load(&bar[132], __ATOMIC_RELAXED, __HIP_MEMORY_SCOPE_AGENT) != 0)
                    break;
            }
            __threadfence();   // acquire: invalidate so subsequent plain loads are fresh
        }
        __syncthreads();
    }
}

// ---------------- fused recurrence: 64 WGs, W resident in LDS ----------------
// WG w: mh = w>>3 (m-pair {2mh,2mh+1}), q = w&7 (e-32-slice). W slice 64 KB in LDS.
// Per step: partial PD[mh][b][e] = sum_{mm} a2[b][2mh+mm]*(W row . zn[b] + tb), all 32 b.
// WGs 0..31 additionally run batch b=wg's phase-1.
__global__ __launch_bounds__(512, 1) void k_rnn(const float* __restrict__ latent,
                                                const int* __restrict__ zi,
                                                const float* __restrict__ anchor_w,
                                                const float* __restrict__ anchor_b,
                                                const float* __restrict__ trans_w,
                                                const float* __restrict__ trans_b,
                                                float* __restrict__ zsf,
                                                float* __restrict__ ZN,
                                                float* __restrict__ PD,
                                                float* __restrict__ A2,
                                                int* __restrict__ bar)
{
    __shared__ float Wl[64][260];     // 66.5 KB  (row r: mm=r>>5, e_local=r&31)
    __shared__ float znl[32][256];    // 32 KB
    __shared__ float xk_l[16][260];   // 16.6 KB (batch WGs)
    __shared__ float xv_l[16][260];   // 16.6 KB
    __shared__ float zl[256];
    __shared__ float a2loc[64];       // [b][mm]
    __shared__ float l1s[16], l2s[16], ab_l[16], rbuf[8];

    const int wg = blockIdx.x, t = threadIdx.x;
    const int mh = wg >> 3, q = wg & 7;
    const int is64 = bar[136];
    const int l = t & 63, wv = t >> 6;

    for (int idx = t; idx < 4096; idx += 512){
        int r = idx >> 6, c = idx & 63;
        int grow = (2*mh + (r >> 5))*256 + q*32 + (r & 31);
        *(float4*)&Wl[r][c*4] = *(const float4*)&trans_w[(size_t)grow*256 + c*4];
    }
    const float tbv = trans_b[(2*mh + (l >> 5))*256 + q*32 + (l & 31)];

    const bool isb = (wg < 32);
    const int b = wg;
    const float* base = nullptr;
    float zn_r = 0.f, em_r = 0.f;
    if (isb){
        int zb = is64 ? zi[2*b] : zi[b];
        base = latent + (size_t)zb * 8192;   // xk=base[0:4096]*100, xv=base[4096:]*100
        for (int i = t; i < 4096; i += 512){
            int s = i >> 8, c = i & 255;
            xk_l[s][c] = base[i];
            xv_l[s][c] = base[4096 + i];
        }
        if (t < 16) ab_l[t] = anchor_b[t];
    }
    __syncthreads();

    int gen = 0;
    for (int stp = 0; stp < NSTEP; ++stp){
        // ---- phase 1 (batch WGs): z -> zn -> att/att2 -> emit; publish ZN/A2 ----
        if (isb){
            float zv = 0.f;
            if (t < 256){
                if (stp == 0) zv = base[t];
                else {
                    float dz = 0.f;
                    #pragma unroll
                    for (int h = 0; h < 8; ++h) dz += PD[(h*32 + b)*256 + t];
                    zv = zn_r + em_r + dz;
                }
                float s1 = wredf(zv), s2 = wredf(zv*zv);
                if ((t & 63) == 0){ rbuf[t>>6] = s1; rbuf[4 + (t>>6)] = s2; }
            }
            __syncthreads();
            if (t < 256){
                float tot1 = rbuf[0]+rbuf[1]+rbuf[2]+rbuf[3];
                float tot2 = rbuf[4]+rbuf[5]+rbuf[6]+rbuf[7];
                float mean = tot1 * (1.0f/EE);
                float var  = (tot2 - (float)EE*mean*mean) * (1.0f/(EE-1));
                var = fmaxf(var, 0.f);
                float sc = 0.113f / (1e-5f + sqrtf(var));
                zn_r = zv * sc;
                zl[t] = zn_r;
                ZN[b*EE + t] = zn_r;
            }
            __syncthreads();
            if (t < 256){
                int sidx = t >> 4, L = t & 15;
                const float* aws = anchor_w + sidx*EE;
                float p1 = 0.f, p2 = 0.f;
                #pragma unroll
                for (int c = 0; c < 16; ++c){
                    int k = L*16 + c;
                    float z = zl[k];
                    p1 += z * xk_l[sidx][k];
                    p2 += z * aws[k];
                }
                #pragma unroll
                for (int mm = 1; mm < 16; mm <<= 1){ p1 += __shfl_xor(p1, mm); p2 += __shfl_xor(p2, mm); }
                if (L == 0){ l1s[sidx] = p1 * 100.0f; l2s[sidx] = p2 + ab_l[sidx]; }
            }
            __syncthreads();
            if (t < 256){
                float mx1 = -1e30f, mx2 = -1e30f;
                #pragma unroll
                for (int s = 0; s < 16; ++s){ mx1 = fmaxf(mx1, l1s[s]); mx2 = fmaxf(mx2, l2s[s]); }
                float att[16]; float sum1 = 0.f, sum2 = 0.f;
                #pragma unroll
                for (int s = 0; s < 16; ++s){
                    att[s] = expf(l1s[s] - mx1); sum1 += att[s];
                    sum2  += expf(l2s[s] - mx2);
                }
                float inv1 = 1.0f / sum1;
                if (t < 16) A2[b*16 + t] = expf(l2s[t] - mx2) / sum2;
                float em = 0.f;
                #pragma unroll
                for (int s = 0; s < 16; ++s) em += (att[s] * inv1) * xv_l[s][t];
                em *= 100.0f;
                em_r = em;
                zsf[((size_t)b*NSTEP + stp)*EE + t] = em;
            }
        }
        if (stp == NSTEP-1) break;
        gen++; gbar(bar, gen);            // ZN/A2 visible

        // ---- D phase (all 64 WGs): stage zn, compute partials ----
        for (int i = t; i < 2048; i += 512){
            int bb = i >> 6, c = i & 63;
            *(float4*)&znl[bb][c*4] = *(const float4*)&ZN[bb*EE + c*4];
        }
        if (t < 64) a2loc[t] = A2[(t >> 1)*16 + 2*mh + (t & 1)];
        __syncthreads();
        {
            const int b0 = wv * 4;
            float4 c0{0,0,0,0}, c1{0,0,0,0}, c2{0,0,0,0}, c3{0,0,0,0};
            #pragma unroll 8
            for (int c = 0; c < 64; ++c){
                float4 w4 = *(const float4*)&Wl[l][c*4];
                float4 z0 = *(const float4*)&znl[b0+0][c*4];
                float4 z1 = *(const float4*)&znl[b0+1][c*4];
                float4 z2 = *(const float4*)&znl[b0+2][c*4];
                float4 z3 = *(const float4*)&znl[b0+3][c*4];
                c0.x += w4.x*z0.x; c0.y += w4.y*z0.y; c0.z += w4.z*z0.z; c0.w += w4.w*z0.w;
                c1.x += w4.x*z1.x; c1.y += w4.y*z1.y; c1.z += w4.z*z1.z; c1.w += w4.w*z1.w;
                c2.x += w4.x*z2.x; c2.y += w4.y*z2.y; c2.z += w4.z*z2.z; c2.w += w4.w*z2.w;
                c3.x += w4.x*z3.x; c3.y += w4.y*z3.y; c3.z += w4.z*z3.z; c3.w += w4.w*z3.w;
            }
            const int mm = l >> 5;
            float u0 = (c0.x+c0.y+c0.z+c0.w + tbv) * a2loc[(b0+0)*2 + mm];
            float u1 = (c1.x+c1.y+c1.z+c1.w + tbv) * a2loc[(b0+1)*2 + mm];
            float u2 = (c2.x+c2.y+c2.z+c2.w + tbv) * a2loc[(b0+2)*2 + mm];
            float u3 = (c3.x+c3.y+c3.z+c3.w + tbv) * a2loc[(b0+3)*2 + mm];
            u0 += __shfl_xor(u0, 32);
            u1 += __shfl_xor(u1, 32);
            u2 += __shfl_xor(u2, 32);
            u3 += __shfl_xor(u3, 32);
            if (l < 32){
                int eb = q*32 + l;
                PD[(mh*32 + b0+0)*256 + eb] = u0;
                PD[(mh*32 + b0+1)*256 + eb] = u1;
                PD[(mh*32 + b0+2)*256 + eb] = u2;
                PD[(mh*32 + b0+3)*256 + eb] = u3;
            }
        }
        gen++; gbar(bar, gen);            // PD visible
    }
}

// ---------------- vocab: f32 VALU logits + streaming sumexp + target ----------
__global__ __launch_bounds__(256) void k_vocab_valu(const float* __restrict__ vw,
                                                    const float* __restrict__ vbias,
                                                    const float* __restrict__ zsf,
                                                    const int* __restrict__ y,
                                                    const int* __restrict__ flag,
                                                    float* __restrict__ pS,
                                                    float* __restrict__ pT)
{
    int rowgrp = blockIdx.x;
    int vs     = blockIdx.y;
    int t = threadIdx.x;

    __shared__ float zl[32][256];
    __shared__ int   yl[32];
    __shared__ float rs[4][32], rt[4][32];

    #pragma unroll
    for (int r = 0; r < 32; ++r) zl[r][t] = zsf[(size_t)(rowgrp*32 + r) * EE + t];
    if (t < 32) yl[t] = flag[0] ? y[2*(rowgrp*32 + t)] : y[rowgrp*32 + t];
    __syncthreads();

    float sums[32], targ[32];
    #pragma unroll
    for (int r = 0; r < 32; ++r){ sums[r] = 0.f; targ[r] = 0.f; }

    for (int p = t; p < 2000; p += 256){
        int n0 = vs*4000 + 2*p, n1 = n0 + 1;
        const float* w0 = vw + (size_t)n0 * EE;
        const float* w1 = w0 + EE;
        float acc0[32], acc1[32];
        #pragma unroll
        for (int r = 0; r < 32; ++r){ acc0[r] = 0.f; acc1[r] = 0.f; }
        for (int k = 0; k < EE; k += 4){
            float4 a = *(const float4*)&w0[k];
            float4 c = *(const float4*)&w1[k];
            #pragma unroll
            for (int r = 0; r < 32; ++r){
                float4 z = *(const float4*)&zl[r][k];
                acc0[r] += z.x*a.x + z.y*a.y + z.z*a.z + z.w*a.w;
                acc1[r] += z.x*c.x + z.y*c.y + z.z*c.z + z.w*c.w;
            }
        }
        float b0 = vbias[n0], b1 = vbias[n1];
        #pragma unroll
        for (int r = 0; r < 32; ++r){
            float v0 = acc0[r] + b0, v1 = acc1[r] + b1;
            sums[r] += expf(v0) + expf(v1);
            if (n0 == yl[r]) targ[r] += v0;
            if (n1 == yl[r]) targ[r] += v1;
        }
    }

    int wv = t >> 6, ln = t & 63;
    #pragma unroll
    for (int r = 0; r < 32; ++r){
        float s = sums[r], g = targ[r];
        #pragma unroll
        for (int mm = 1; mm < 64; mm <<= 1){ s += __shfl_xor(s, mm); g += __shfl_xor(g, mm); }
        if (ln == 0){ rs[wv][r] = s; rt[wv][r] = g; }
    }
    __syncthreads();
    if (t < 32){
        float s = rs[0][t] + rs[1][t] + rs[2][t] + rs[3][t];
        float g = rt[0][t] + rt[1][t] + rt[2][t] + rt[3][t];
        int r = rowgrp*32 + t;
        pS[(size_t)vs*ROWS + r] = s;
        pT[(size_t)vs*ROWS + r] = g;
    }
}

__global__ __launch_bounds__(256) void k_final(const float* __restrict__ pS,
                                               const float* __restrict__ pT,
                                               const int* __restrict__ bar,
                                               float* __restrict__ outp)
{
    int r = blockIdx.x * 256 + threadIdx.x;
    float s = 0.f, g = 0.f;
    #pragma unroll
    for (int i = 0; i < VSPLIT; ++i){ s += pS[(size_t)i*ROWS + r]; g += pT[(size_t)i*ROWS + r]; }
    float v = g - logf(s);
    if (bar[132] != 0) v = 4000.0f;    // barrier timeout sentinel
    outp[r] = v;
}

extern "C" void kernel_launch(void* const* d_in, const int* in_sizes, int n_in,
                              void* d_out, int out_size, void* d_ws, size_t ws_size,
                              hipStream_t stream)
{
    (void)out_size;
    const float* latent   = (const float*)d_in[0];
    const float* trans_w  = (const float*)d_in[1];
    const float* trans_b  = (const float*)d_in[2];
    const float* anchor_w = (const float*)d_in[3];
    const float* anchor_b = (const float*)d_in[4];
    const float* vocab_w  = (const float*)d_in[5];
    const float* vocab_b  = (const float*)d_in[6];
    const int*   zi       = (const int*)d_in[7];
    const int*   y        = (const int*)d_in[8];

    float* outp = (float*)d_out;

    if (ws_size < (size_t)WS_REQ){ k_sentinel<<<16, 256, 0, stream>>>(outp, 2000.0f); return; }
    {
        bool ok = (n_in >= 9)
               && in_sizes[0] == 67108864 && in_sizes[1] == 1048576
               && in_sizes[2] == 4096     && in_sizes[3] == 4096
               && in_sizes[4] == 16       && in_sizes[5] == 8192000
               && in_sizes[6] == 32000
               && (in_sizes[7] == 32   || in_sizes[7] == 64)
               && (in_sizes[8] == 4096 || in_sizes[8] == 8192);
        if (!ok){ k_sentinel<<<16, 256, 0, stream>>>(outp, 2100.0f); return; }
    }

    char* ws = (char*)d_ws;
    float* zsf = (float*)(ws + OFF_ZSF);
    float* PD  = (float*)(ws + OFF_PD);
    float* pS  = (float*)(ws + OFF_PS);
    float* pT  = (float*)(ws + OFF_PT);
    float* ZN  = (float*)(ws + OFF_ZN);
    float* A2  = (float*)(ws + OFF_A2);
    int*   bar = (int*)(ws + OFF_BAR);

    k_prep<<<1, 256, 0, stream>>>(zi, bar);

    k_rnn<<<NWGR, 512, 0, stream>>>(latent, zi, anchor_w, anchor_b,
                                    trans_w, trans_b, zsf, ZN, PD, A2, bar);

    k_vocab_valu<<<dim3(128, VSPLIT), 256, 0, stream>>>(vocab_w, vocab_b, zsf, y,
                                                        bar + 136, pS, pT);
    k_final<<<16, 256, 0, stream>>>(pS, pT, bar, outp);
}

// Round 11
// 2427.393 us; speedup vs baseline: 4.4182x; 1.6045x over previous
//
#include <hip/hip_runtime.h>

#define EE 256
#define GG 32000
#define NSTEP 128
#define ROWS 4096
#define VSPLIT 4
#define NWGR 64

typedef __attribute__((ext_vector_type(8))) short bf16x8;
typedef __attribute__((ext_vector_type(4))) float f32x4;

// ---------- workspace layout (bytes) ----------
#define OFF_ZSB  0u                     // bf16 zs 4096x256 = 2 MB
#define OFF_PS   2097152u               // f32 4x4096 = 64 KB
#define OFF_PT   (OFF_PS + 65536u)      // 64 KB
#define OFF_ZN   (OFF_PT + 65536u)      // 32 KB
#define OFF_A2   (OFF_ZN + 32768u)      // 4 KB
#define OFF_BAR  (OFF_A2 + 4096u)       // 4 KB ints
#define OFF_PD   (OFF_BAR + 4096u)      // 256 KB
#define WS_REQ   (OFF_PD + 262144u)     // 2,531,328 B  (< confirmed 4,460,544)
#define OFF_VB   WS_REQ                 // optional bf16 vocab 16,384,000 B
#define VB_BYTES 16384000u

// bar int slots: flags[1..63], rel@128, dead@132, mfmachk@133, is64@136

__device__ __forceinline__ float wredf(float v){
    #pragma unroll
    for (int m = 1; m < 64; m <<= 1) v += __shfl_xor(v, m);
    return v;
}
__device__ __forceinline__ unsigned short f2bf_bits(float f){
    unsigned int u = __float_as_uint(f);
    unsigned int lsb = (u >> 16) & 1u;
    u += 0x7fffu + lsb;
    return (unsigned short)(u >> 16);
}
__device__ __forceinline__ float bf2f(unsigned short u){
    return __uint_as_float(((unsigned int)u) << 16);
}

__global__ __launch_bounds__(256) void k_sentinel(float* __restrict__ outp, float val){
    int r = blockIdx.x * 256 + threadIdx.x;
    outp[r] = val;
}

__global__ void k_prep(const int* __restrict__ zi, int* __restrict__ bar){
    int t = threadIdx.x;
    bar[t] = 0;            // re-zeroed EVERY replay
    __syncthreads();
    if (t == 0){
        bool odd_zero = true, even_ok = true;
        for (int i = 0; i < 16; ++i){
            int lo = zi[2*i], hi = zi[2*i+1];
            if (hi != 0) odd_zero = false;
            if (lo < 0 || lo >= 8192) even_ok = false;
        }
        bar[136] = (odd_zero && even_ok) ? 1 : 0;
    }
}

// ---------------- vocab f32 -> bf16 (RNE, matches pack8f) ----------------
__global__ __launch_bounds__(256) void k_cvt(const float* __restrict__ in,
                                             unsigned short* __restrict__ outp)
{
    int i = (blockIdx.x * 256 + threadIdx.x) * 4;
    float4 v = *(const float4*)&in[i];
    ushort4 o;
    o.x = f2bf_bits(v.x); o.y = f2bf_bits(v.y);
    o.z = f2bf_bits(v.z); o.w = f2bf_bits(v.w);
    *(ushort4*)&outp[i] = o;
}

// ---- grid barrier: round-10-proven (fence + atomic flags, 2-stage release) ----
__device__ __forceinline__ void gbar(int* __restrict__ bar, int gen){
    __syncthreads();
    const int t = threadIdx.x, wg = blockIdx.x;
    if (wg == 0){
        if (t >= 1 && t < NWGR){
            int spins = 0;
            while (__hip_atomic_load(&bar[t], __ATOMIC_RELAXED, __HIP_MEMORY_SCOPE_AGENT) < gen){
                __builtin_amdgcn_s_sleep(2);
                if (++spins > 1000000){
                    __hip_atomic_store(&bar[132], 1, __ATOMIC_RELAXED, __HIP_MEMORY_SCOPE_AGENT);
                    break;
                }
                if ((spins & 2047) == 0 &&
                    __hip_atomic_load(&bar[132], __ATOMIC_RELAXED, __HIP_MEMORY_SCOPE_AGENT) != 0)
                    break;
            }
        }
        __syncthreads();
        if (t == 0){
            __threadfence();
            __hip_atomic_store(&bar[128], gen, __ATOMIC_RELAXED, __HIP_MEMORY_SCOPE_AGENT);
        }
        __syncthreads();
    } else {
        if (t == 0){
            __threadfence();
            __hip_atomic_store(&bar[wg], gen, __ATOMIC_RELAXED, __HIP_MEMORY_SCOPE_AGENT);
            int spins = 0;
            while (__hip_atomic_load(&bar[128], __ATOMIC_RELAXED, __HIP_MEMORY_SCOPE_AGENT) < gen){
                __builtin_amdgcn_s_sleep(2);
                if (++spins > 1000000){
                    __hip_atomic_store(&bar[132], 1, __ATOMIC_RELAXED, __HIP_MEMORY_SCOPE_AGENT);
                    break;
                }
                if ((spins & 2047) == 0 &&
                    __hip_atomic_load(&bar[132], __ATOMIC_RELAXED, __HIP_MEMORY_SCOPE_AGENT) != 0)
                    break;
            }
            __threadfence();
        }
        __syncthreads();
    }
}

// ---------------- fused recurrence: 64 WGs, W resident in LDS (round 10) -------
__global__ __launch_bounds__(512, 1) void k_rnn(const float* __restrict__ latent,
                                                const int* __restrict__ zi,
                                                const float* __restrict__ anchor_w,
                                                const float* __restrict__ anchor_b,
                                                const float* __restrict__ trans_w,
                                                const float* __restrict__ trans_b,
                                                unsigned short* __restrict__ zsb,
                                                float* __restrict__ ZN,
                                                float* __restrict__ PD,
                                                float* __restrict__ A2,
                                                int* __restrict__ bar)
{
    __shared__ float Wl[64][260];
    __shared__ float znl[32][256];
    __shared__ float xk_l[16][260];
    __shared__ float xv_l[16][260];
    __shared__ float zl[256];
    __shared__ float a2loc[64];
    __shared__ float l1s[16], l2s[16], ab_l[16], rbuf[8];

    const int wg = blockIdx.x, t = threadIdx.x;
    const int mh = wg >> 3, q = wg & 7;
    const int is64 = bar[136];
    const int l = t & 63, wv = t >> 6;

    for (int idx = t; idx < 4096; idx += 512){
        int r = idx >> 6, c = idx & 63;
        int grow = (2*mh + (r >> 5))*256 + q*32 + (r & 31);
        *(float4*)&Wl[r][c*4] = *(const float4*)&trans_w[(size_t)grow*256 + c*4];
    }
    const float tbv = trans_b[(2*mh + (l >> 5))*256 + q*32 + (l & 31)];

    const bool isb = (wg < 32);
    const int b = wg;
    const float* base = nullptr;
    float zn_r = 0.f, em_r = 0.f;
    if (isb){
        int zb = is64 ? zi[2*b] : zi[b];
        base = latent + (size_t)zb * 8192;   // xk=base[0:4096]*100, xv=base[4096:]*100
        for (int i = t; i < 4096; i += 512){
            int s = i >> 8, c = i & 255;
            xk_l[s][c] = base[i];
            xv_l[s][c] = base[4096 + i];
        }
        if (t < 16) ab_l[t] = anchor_b[t];
    }
    __syncthreads();

    int gen = 0;
    for (int stp = 0; stp < NSTEP; ++stp){
        if (isb){
            float zv = 0.f;
            if (t < 256){
                if (stp == 0) zv = base[t];
                else {
                    float dz = 0.f;
                    #pragma unroll
                    for (int h = 0; h < 8; ++h) dz += PD[(h*32 + b)*256 + t];
                    zv = zn_r + em_r + dz;
                }
                float s1 = wredf(zv), s2 = wredf(zv*zv);
                if ((t & 63) == 0){ rbuf[t>>6] = s1; rbuf[4 + (t>>6)] = s2; }
            }
            __syncthreads();
            if (t < 256){
                float tot1 = rbuf[0]+rbuf[1]+rbuf[2]+rbuf[3];
                float tot2 = rbuf[4]+rbuf[5]+rbuf[6]+rbuf[7];
                float mean = tot1 * (1.0f/EE);
                float var  = (tot2 - (float)EE*mean*mean) * (1.0f/(EE-1));
                var = fmaxf(var, 0.f);
                float sc = 0.113f / (1e-5f + sqrtf(var));
                zn_r = zv * sc;
                zl[t] = zn_r;
                ZN[b*EE + t] = zn_r;
            }
            __syncthreads();
            if (t < 256){
                int sidx = t >> 4, L = t & 15;
                const float* aws = anchor_w + sidx*EE;
                float p1 = 0.f, p2 = 0.f;
                #pragma unroll
                for (int c = 0; c < 16; ++c){
                    int k = L*16 + c;
                    float z = zl[k];
                    p1 += z * xk_l[sidx][k];
                    p2 += z * aws[k];
                }
                #pragma unroll
                for (int mm = 1; mm < 16; mm <<= 1){ p1 += __shfl_xor(p1, mm); p2 += __shfl_xor(p2, mm); }
                if (L == 0){ l1s[sidx] = p1 * 100.0f; l2s[sidx] = p2 + ab_l[sidx]; }
            }
            __syncthreads();
            if (t < 256){
                float mx1 = -1e30f, mx2 = -1e30f;
                #pragma unroll
                for (int s = 0; s < 16; ++s){ mx1 = fmaxf(mx1, l1s[s]); mx2 = fmaxf(mx2, l2s[s]); }
                float att[16]; float sum1 = 0.f, sum2 = 0.f;
                #pragma unroll
                for (int s = 0; s < 16; ++s){
                    att[s] = expf(l1s[s] - mx1); sum1 += att[s];
                    sum2  += expf(l2s[s] - mx2);
                }
                float inv1 = 1.0f / sum1;
                if (t < 16) A2[b*16 + t] = expf(l2s[t] - mx2) / sum2;
                float em = 0.f;
                #pragma unroll
                for (int s = 0; s < 16; ++s) em += (att[s] * inv1) * xv_l[s][t];
                em *= 100.0f;
                em_r = em;
                zsb[((size_t)b*NSTEP + stp)*EE + t] = f2bf_bits(em);
            }
        }
        if (stp == NSTEP-1) break;
        gen++; gbar(bar, gen);            // ZN/A2 visible

        for (int i = t; i < 2048; i += 512){
            int bb = i >> 6, c = i & 63;
            *(float4*)&znl[bb][c*4] = *(const float4*)&ZN[bb*EE + c*4];
        }
        if (t < 64) a2loc[t] = A2[(t >> 1)*16 + 2*mh + (t & 1)];
        __syncthreads();
        {
            const int b0 = wv * 4;
            float4 c0{0,0,0,0}, c1{0,0,0,0}, c2{0,0,0,0}, c3{0,0,0,0};
            #pragma unroll 8
            for (int c = 0; c < 64; ++c){
                float4 w4 = *(const float4*)&Wl[l][c*4];
                float4 z0 = *(const float4*)&znl[b0+0][c*4];
                float4 z1 = *(const float4*)&znl[b0+1][c*4];
                float4 z2 = *(const float4*)&znl[b0+2][c*4];
                float4 z3 = *(const float4*)&znl[b0+3][c*4];
                c0.x += w4.x*z0.x; c0.y += w4.y*z0.y; c0.z += w4.z*z0.z; c0.w += w4.w*z0.w;
                c1.x += w4.x*z1.x; c1.y += w4.y*z1.y; c1.z += w4.z*z1.z; c1.w += w4.w*z1.w;
                c2.x += w4.x*z2.x; c2.y += w4.y*z2.y; c2.z += w4.z*z2.z; c2.w += w4.w*z2.w;
                c3.x += w4.x*z3.x; c3.y += w4.y*z3.y; c3.z += w4.z*z3.z; c3.w += w4.w*z3.w;
            }
            const int mm = l >> 5;
            float u0 = (c0.x+c0.y+c0.z+c0.w + tbv) * a2loc[(b0+0)*2 + mm];
            float u1 = (c1.x+c1.y+c1.z+c1.w + tbv) * a2loc[(b0+1)*2 + mm];
            float u2 = (c2.x+c2.y+c2.z+c2.w + tbv) * a2loc[(b0+2)*2 + mm];
            float u3 = (c3.x+c3.y+c3.z+c3.w + tbv) * a2loc[(b0+3)*2 + mm];
            u0 += __shfl_xor(u0, 32);
            u1 += __shfl_xor(u1, 32);
            u2 += __shfl_xor(u2, 32);
            u3 += __shfl_xor(u3, 32);
            if (l < 32){
                int eb = q*32 + l;
                PD[(mh*32 + b0+0)*256 + eb] = u0;
                PD[(mh*32 + b0+1)*256 + eb] = u1;
                PD[(mh*32 + b0+2)*256 + eb] = u2;
                PD[(mh*32 + b0+3)*256 + eb] = u3;
            }
        }
        gen++; gbar(bar, gen);            // PD visible
    }
}

// ---------------- vocab: bf16 MFMA logits + streaming sumexp + target ----------
__device__ __forceinline__ bf16x8 pack8f(const float* __restrict__ src){
    bf16x8 r;
    #pragma unroll
    for (int j = 0; j < 8; ++j) r[j] = (short)f2bf_bits(src[j]);
    return r;
}

template<bool VB>
__global__ __launch_bounds__(256, 1) void k_vocab(const unsigned short* __restrict__ vb,
                                                  const float* __restrict__ vwf,
                                                  const float* __restrict__ vbias,
                                                  const unsigned short* __restrict__ zsb,
                                                  const int* __restrict__ y,
                                                  float* __restrict__ pS,
                                                  float* __restrict__ pT,
                                                  int* __restrict__ bar)
{
    const int rowblk = blockIdx.x;   // 0..63  (64 rows each)
    const int split  = blockIdx.y;   // 0..3   (8000 vocab cols each)
    const int t = threadIdx.x;
    const int wave = t >> 6, lane = t & 63;
    const int kg = lane >> 4, nl = lane & 15;
    const int is64 = bar[136];

    __shared__ float psum_l[4][64];
    __shared__ float ptarg_l[4][64];
    __shared__ float chk[1];

    // A fragments: 64 zs-rows x 256 k in registers.
    // lane holds A[row = mt*16 + nl][k = kk*32 + kg*8 + j]
    bf16x8 afr[4][8];
    #pragma unroll
    for (int mt = 0; mt < 4; ++mt)
        #pragma unroll
        for (int kk = 0; kk < 8; ++kk)
            afr[mt][kk] = *(const bf16x8*)&zsb[(size_t)(rowblk*64 + mt*16 + nl) * EE + kk*32 + kg*8];

    // C/D rows owned by this lane: row = mt*16 + kg*4 + i
    int tg[4][4];
    #pragma unroll
    for (int mt = 0; mt < 4; ++mt)
        #pragma unroll
        for (int i = 0; i < 4; ++i){
            int rg = rowblk*64 + mt*16 + kg*4 + i;
            tg[mt][i] = is64 ? y[2*rg] : y[rg];
        }

    float sums[4][4]; float targ[4][4];
    #pragma unroll
    for (int mt = 0; mt < 4; ++mt)
        #pragma unroll
        for (int i = 0; i < 4; ++i){ sums[mt][i] = 0.f; targ[mt][i] = 0.f; }

    for (int tile = wave; tile < 500; tile += 4){
        int n = split*8000 + tile*16 + nl;   // this lane's vocab column
        f32x4 acc[4];
        #pragma unroll
        for (int mt = 0; mt < 4; ++mt) acc[mt] = (f32x4){0.f,0.f,0.f,0.f};
        #pragma unroll
        for (int kk = 0; kk < 8; ++kk){
            bf16x8 bfr;
            if (VB) bfr = *(const bf16x8*)&vb[(size_t)n * EE + kk*32 + kg*8];
            else    bfr = pack8f(&vwf[(size_t)n * EE + kk*32 + kg*8]);
            #pragma unroll
            for (int mt = 0; mt < 4; ++mt)
                acc[mt] = __builtin_amdgcn_mfma_f32_16x16x32_bf16(afr[mt][kk], bfr, acc[mt], 0, 0, 0);
        }
        float bias = vbias[n];
        if (rowblk == 0 && split == 0 && t == 0 && tile == 0)
            chk[0] = acc[0][0] + bias;     // L[row 0][col 0] per MFMA
        #pragma unroll
        for (int mt = 0; mt < 4; ++mt)
            #pragma unroll
            for (int i = 0; i < 4; ++i){
                float v = acc[mt][i] + bias;
                sums[mt][i] += expf(v);
                if (n == tg[mt][i]) targ[mt][i] += v;
            }
    }

    // reduce over the 16 column-lanes sharing the same rows
    #pragma unroll
    for (int mt = 0; mt < 4; ++mt)
        #pragma unroll
        for (int i = 0; i < 4; ++i){
            float sv = sums[mt][i], tv = targ[mt][i];
            #pragma unroll
            for (int msk = 1; msk < 16; msk <<= 1){ sv += __shfl_xor(sv, msk); tv += __shfl_xor(tv, msk); }
            if (nl == 0){ int row = mt*16 + kg*4 + i; psum_l[wave][row] = sv; ptarg_l[wave][row] = tv; }
        }
    __syncthreads();
    if (t < 64){
        float sv = psum_l[0][t] + psum_l[1][t] + psum_l[2][t] + psum_l[3][t];
        float tv = ptarg_l[0][t] + ptarg_l[1][t] + ptarg_l[2][t] + ptarg_l[3][t];
        int r = rowblk*64 + t;
        pS[(size_t)split*ROWS + r] = sv;
        pT[(size_t)split*ROWS + r] = tv;
    }

    // MFMA layout self-check: scalar bf16 dot of row 0 x col 0
    if (rowblk == 0 && split == 0 && t == 0){
        float s = 0.f;
        for (int k = 0; k < EE; ++k){
            float a = bf2f(zsb[k]);
            float w = VB ? bf2f(vb[k]) : bf2f(f2bf_bits(vwf[k]));
            s += a * w;
        }
        s += vbias[0];
        if (fabsf(s - chk[0]) > 0.02f) bar[133] = 1;
    }
}

__global__ __launch_bounds__(256) void k_final(const float* __restrict__ pS,
                                               const float* __restrict__ pT,
                                               const int* __restrict__ bar,
                                               float* __restrict__ outp)
{
    int r = blockIdx.x * 256 + threadIdx.x;
    float s = 0.f, g = 0.f;
    #pragma unroll
    for (int i = 0; i < VSPLIT; ++i){ s += pS[(size_t)i*ROWS + r]; g += pT[(size_t)i*ROWS + r]; }
    float v = g - logf(s);
    if (bar[132] != 0) v = 4000.0f;    // barrier timeout sentinel
    if (bar[133] != 0) v = 5000.0f;    // MFMA layout mismatch sentinel
    outp[r] = v;
}

extern "C" void kernel_launch(void* const* d_in, const int* in_sizes, int n_in,
                              void* d_out, int out_size, void* d_ws, size_t ws_size,
                              hipStream_t stream)
{
    (void)out_size;
    const float* latent   = (const float*)d_in[0];
    const float* trans_w  = (const float*)d_in[1];
    const float* trans_b  = (const float*)d_in[2];
    const float* anchor_w = (const float*)d_in[3];
    const float* anchor_b = (const float*)d_in[4];
    const float* vocab_w  = (const float*)d_in[5];
    const float* vocab_b  = (const float*)d_in[6];
    const int*   zi       = (const int*)d_in[7];
    const int*   y        = (const int*)d_in[8];

    float* outp = (float*)d_out;

    if (ws_size < (size_t)WS_REQ){ k_sentinel<<<16, 256, 0, stream>>>(outp, 2000.0f); return; }
    {
        bool ok = (n_in >= 9)
               && in_sizes[0] == 67108864 && in_sizes[1] == 1048576
               && in_sizes[2] == 4096     && in_sizes[3] == 4096
               && in_sizes[4] == 16       && in_sizes[5] == 8192000
               && in_sizes[6] == 32000
               && (in_sizes[7] == 32   || in_sizes[7] == 64)
               && (in_sizes[8] == 4096 || in_sizes[8] == 8192);
        if (!ok){ k_sentinel<<<16, 256, 0, stream>>>(outp, 2100.0f); return; }
    }

    char* ws = (char*)d_ws;
    unsigned short* zsb = (unsigned short*)(ws + OFF_ZSB);
    float* pS  = (float*)(ws + OFF_PS);
    float* pT  = (float*)(ws + OFF_PT);
    float* ZN  = (float*)(ws + OFF_ZN);
    float* A2  = (float*)(ws + OFF_A2);
    int*   bar = (int*)(ws + OFF_BAR);
    float* PD  = (float*)(ws + OFF_PD);
    unsigned short* vbu = (unsigned short*)(ws + OFF_VB);

    const bool use_vb = ws_size >= (size_t)OFF_VB + (size_t)VB_BYTES;

    k_prep<<<1, 256, 0, stream>>>(zi, bar);
    if (use_vb)
        k_cvt<<<GG*EE/1024, 256, 0, stream>>>(vocab_w, vbu);

    k_rnn<<<NWGR, 512, 0, stream>>>(latent, zi, anchor_w, anchor_b,
                                    trans_w, trans_b, zsb, ZN, PD, A2, bar);

    if (use_vb)
        k_vocab<true><<<dim3(64, VSPLIT), 256, 0, stream>>>(vbu, nullptr, vocab_b,
                                                            zsb, y, pS, pT, bar);
    else
        k_vocab<false><<<dim3(64, VSPLIT), 256, 0, stream>>>(nullptr, vocab_w, vocab_b,
                                                             zsb, y, pS, pT, bar);

    k_final<<<16, 256, 0, stream>>>(pS, pT, bar, outp);
}

// Round 12
// 2310.670 us; speedup vs baseline: 4.6414x; 1.0505x over previous
//
#include <hip/hip_runtime.h>

#define EE 256
#define GG 32000
#define NSTEP 128
#define ROWS 4096
#define VSPLIT 4
#define NWGR 64

typedef __attribute__((ext_vector_type(8))) short bf16x8;
typedef __attribute__((ext_vector_type(4))) float f32x4;

// ---------- workspace layout (bytes) ----------
#define OFF_ZSB  0u                     // bf16 zs 4096x256 = 2 MB
#define OFF_PS   2097152u               // f32 4x4096 = 64 KB
#define OFF_PT   (OFF_PS + 65536u)      // 64 KB
#define OFF_ZN   (OFF_PT + 65536u)      // 32 KB
#define OFF_A2   (OFF_ZN + 32768u)      // 4 KB
#define OFF_BAR  (OFF_A2 + 4096u)       // 4 KB ints
#define OFF_PD   (OFF_BAR + 4096u)      // 256 KB
#define WS_REQ   (OFF_PD + 262144u)     // 2,531,328 B
#define OFF_VB   WS_REQ                 // optional bf16 vocab 16,384,000 B
#define VB_BYTES 16384000u

// bar int slots: flags[1..63], rel@128, dead@132, mfmachk@133, is64@136

__device__ __forceinline__ float wredf(float v){
    #pragma unroll
    for (int m = 1; m < 64; m <<= 1) v += __shfl_xor(v, m);
    return v;
}
__device__ __forceinline__ unsigned short f2bf_bits(float f){
    unsigned int u = __float_as_uint(f);
    unsigned int lsb = (u >> 16) & 1u;
    u += 0x7fffu + lsb;
    return (unsigned short)(u >> 16);
}
__device__ __forceinline__ float bf2f(unsigned short u){
    return __uint_as_float(((unsigned int)u) << 16);
}
// coherent-point (LLC) data access: same primitive as the proven barrier flags
__device__ __forceinline__ float aload(const float* p){
    return __hip_atomic_load(p, __ATOMIC_RELAXED, __HIP_MEMORY_SCOPE_AGENT);
}
__device__ __forceinline__ void astore(float* p, float v){
    __hip_atomic_store(p, v, __ATOMIC_RELAXED, __HIP_MEMORY_SCOPE_AGENT);
}

__global__ __launch_bounds__(256) void k_sentinel(float* __restrict__ outp, float val){
    int r = blockIdx.x * 256 + threadIdx.x;
    outp[r] = val;
}

__global__ void k_prep(const int* __restrict__ zi, int* __restrict__ bar){
    int t = threadIdx.x;
    bar[t] = 0;            // re-zeroed EVERY replay
    __syncthreads();
    if (t == 0){
        bool odd_zero = true, even_ok = true;
        for (int i = 0; i < 16; ++i){
            int lo = zi[2*i], hi = zi[2*i+1];
            if (hi != 0) odd_zero = false;
            if (lo < 0 || lo >= 8192) even_ok = false;
        }
        bar[136] = (odd_zero && even_ok) ? 1 : 0;
    }
}

// ---------------- vocab f32 -> bf16 (RNE, matches pack8f) ----------------
__global__ __launch_bounds__(256) void k_cvt(const float* __restrict__ in,
                                             unsigned short* __restrict__ outp)
{
    int i = (blockIdx.x * 256 + threadIdx.x) * 4;
    float4 v = *(const float4*)&in[i];
    ushort4 o;
    o.x = f2bf_bits(v.x); o.y = f2bf_bits(v.y);
    o.z = f2bf_bits(v.z); o.w = f2bf_bits(v.w);
    *(ushort4*)&outp[i] = o;
}

// ---- grid barrier: FENCE-FREE (flags only; data goes via LLC atomics) ----
// store-side ordering: __syncthreads drains vmcnt(0) => all atomic data stores
// acked at the coherent point before the flag store issues.
// load-side ordering: poll-loop branch dependence + sched_barrier(0).
__device__ __forceinline__ void gbar(int* __restrict__ bar, int gen){
    __syncthreads();
    const int t = threadIdx.x, wg = blockIdx.x;
    if (wg == 0){
        if (t >= 1 && t < NWGR){
            int spins = 0;
            while (__hip_atomic_load(&bar[t], __ATOMIC_RELAXED, __HIP_MEMORY_SCOPE_AGENT) < gen){
                __builtin_amdgcn_s_sleep(1);
                if (++spins > 2000000){
                    __hip_atomic_store(&bar[132], 1, __ATOMIC_RELAXED, __HIP_MEMORY_SCOPE_AGENT);
                    break;
                }
                if ((spins & 2047) == 0 &&
                    __hip_atomic_load(&bar[132], __ATOMIC_RELAXED, __HIP_MEMORY_SCOPE_AGENT) != 0)
                    break;
            }
        }
        __syncthreads();
        if (t == 0)
            __hip_atomic_store(&bar[128], gen, __ATOMIC_RELAXED, __HIP_MEMORY_SCOPE_AGENT);
        __syncthreads();
    } else {
        if (t == 0){
            __hip_atomic_store(&bar[wg], gen, __ATOMIC_RELAXED, __HIP_MEMORY_SCOPE_AGENT);
            int spins = 0;
            while (__hip_atomic_load(&bar[128], __ATOMIC_RELAXED, __HIP_MEMORY_SCOPE_AGENT) < gen){
                __builtin_amdgcn_s_sleep(1);
                if (++spins > 2000000){
                    __hip_atomic_store(&bar[132], 1, __ATOMIC_RELAXED, __HIP_MEMORY_SCOPE_AGENT);
                    break;
                }
                if ((spins & 2047) == 0 &&
                    __hip_atomic_load(&bar[132], __ATOMIC_RELAXED, __HIP_MEMORY_SCOPE_AGENT) != 0)
                    break;
            }
        }
        __syncthreads();
    }
    __builtin_amdgcn_sched_barrier(0);   // keep post-barrier loads below the poll
}

// ---------------- fused recurrence: 64 WGs, W resident in LDS ----------------
__global__ __launch_bounds__(512, 1) void k_rnn(const float* __restrict__ latent,
                                                const int* __restrict__ zi,
                                                const float* __restrict__ anchor_w,
                                                const float* __restrict__ anchor_b,
                                                const float* __restrict__ trans_w,
                                                const float* __restrict__ trans_b,
                                                unsigned short* __restrict__ zsb,
                                                float* __restrict__ ZN,
                                                float* __restrict__ PD,
                                                float* __restrict__ A2,
                                                int* __restrict__ bar)
{
    __shared__ float Wl[64][260];
    __shared__ float znl[32][256];
    __shared__ float xk_l[16][260];
    __shared__ float xv_l[16][260];
    __shared__ float zl[256];
    __shared__ float a2loc[64];
    __shared__ float l1s[16], l2s[16], ab_l[16], rbuf[8];

    const int wg = blockIdx.x, t = threadIdx.x;
    const int mh = wg >> 3, q = wg & 7;
    const int is64 = bar[136];
    const int l = t & 63, wv = t >> 6;

    for (int idx = t; idx < 4096; idx += 512){
        int r = idx >> 6, c = idx & 63;
        int grow = (2*mh + (r >> 5))*256 + q*32 + (r & 31);
        *(float4*)&Wl[r][c*4] = *(const float4*)&trans_w[(size_t)grow*256 + c*4];
    }
    const float tbv = trans_b[(2*mh + (l >> 5))*256 + q*32 + (l & 31)];

    const bool isb = (wg < 32);
    const int b = wg;
    const float* base = nullptr;
    float zn_r = 0.f, em_r = 0.f;
    if (isb){
        int zb = is64 ? zi[2*b] : zi[b];
        base = latent + (size_t)zb * 8192;   // xk=base[0:4096]*100, xv=base[4096:]*100
        for (int i = t; i < 4096; i += 512){
            int s = i >> 8, c = i & 255;
            xk_l[s][c] = base[i];
            xv_l[s][c] = base[4096 + i];
        }
        if (t < 16) ab_l[t] = anchor_b[t];
    }
    __syncthreads();

    int gen = 0;
    for (int stp = 0; stp < NSTEP; ++stp){
        if (isb){
            float zv = 0.f;
            if (t < 256){
                if (stp == 0) zv = base[t];
                else {
                    float dz = 0.f;
                    #pragma unroll
                    for (int h = 0; h < 8; ++h) dz += aload(&PD[(h*32 + b)*256 + t]);
                    zv = zn_r + em_r + dz;
                }
                float s1 = wredf(zv), s2 = wredf(zv*zv);
                if ((t & 63) == 0){ rbuf[t>>6] = s1; rbuf[4 + (t>>6)] = s2; }
            }
            __syncthreads();
            if (t < 256){
                float tot1 = rbuf[0]+rbuf[1]+rbuf[2]+rbuf[3];
                float tot2 = rbuf[4]+rbuf[5]+rbuf[6]+rbuf[7];
                float mean = tot1 * (1.0f/EE);
                float var  = (tot2 - (float)EE*mean*mean) * (1.0f/(EE-1));
                var = fmaxf(var, 0.f);
                float sc = 0.113f / (1e-5f + sqrtf(var));
                zn_r = zv * sc;
                zl[t] = zn_r;
                astore(&ZN[b*EE + t], zn_r);
            }
            __syncthreads();
            if (t < 256){
                int sidx = t >> 4, L = t & 15;
                const float* aws = anchor_w + sidx*EE;
                float p1 = 0.f, p2 = 0.f;
                #pragma unroll
                for (int c = 0; c < 16; ++c){
                    int k = L*16 + c;
                    float z = zl[k];
                    p1 += z * xk_l[sidx][k];
                    p2 += z * aws[k];
                }
                #pragma unroll
                for (int mm = 1; mm < 16; mm <<= 1){ p1 += __shfl_xor(p1, mm); p2 += __shfl_xor(p2, mm); }
                if (L == 0){ l1s[sidx] = p1 * 100.0f; l2s[sidx] = p2 + ab_l[sidx]; }
            }
            __syncthreads();
            if (t < 256){
                float mx1 = -1e30f, mx2 = -1e30f;
                #pragma unroll
                for (int s = 0; s < 16; ++s){ mx1 = fmaxf(mx1, l1s[s]); mx2 = fmaxf(mx2, l2s[s]); }
                float att[16]; float sum1 = 0.f, sum2 = 0.f;
                #pragma unroll
                for (int s = 0; s < 16; ++s){
                    att[s] = expf(l1s[s] - mx1); sum1 += att[s];
                    sum2  += expf(l2s[s] - mx2);
                }
                float inv1 = 1.0f / sum1;
                if (t < 16) astore(&A2[b*16 + t], expf(l2s[t] - mx2) / sum2);
                float em = 0.f;
                #pragma unroll
                for (int s = 0; s < 16; ++s) em += (att[s] * inv1) * xv_l[s][t];
                em *= 100.0f;
                em_r = em;
                zsb[((size_t)b*NSTEP + stp)*EE + t] = f2bf_bits(em);
            }
        }
        if (stp == NSTEP-1) break;
        gen++; gbar(bar, gen);            // ZN/A2 visible (LLC)

        for (int i = t; i < 8192; i += 512){
            int bb = i >> 8, c = i & 255;
            znl[bb][c] = aload(&ZN[bb*EE + c]);
        }
        if (t < 64) a2loc[t] = aload(&A2[(t >> 1)*16 + 2*mh + (t & 1)]);
        __syncthreads();
        {
            const int b0 = wv * 4;
            float4 c0{0,0,0,0}, c1{0,0,0,0}, c2{0,0,0,0}, c3{0,0,0,0};
            #pragma unroll 8
            for (int c = 0; c < 64; ++c){
                float4 w4 = *(const float4*)&Wl[l][c*4];
                float4 z0 = *(const float4*)&znl[b0+0][c*4];
                float4 z1 = *(const float4*)&znl[b0+1][c*4];
                float4 z2 = *(const float4*)&znl[b0+2][c*4];
                float4 z3 = *(const float4*)&znl[b0+3][c*4];
                c0.x += w4.x*z0.x; c0.y += w4.y*z0.y; c0.z += w4.z*z0.z; c0.w += w4.w*z0.w;
                c1.x += w4.x*z1.x; c1.y += w4.y*z1.y; c1.z += w4.z*z1.z; c1.w += w4.w*z1.w;
                c2.x += w4.x*z2.x; c2.y += w4.y*z2.y; c2.z += w4.z*z2.z; c2.w += w4.w*z2.w;
                c3.x += w4.x*z3.x; c3.y += w4.y*z3.y; c3.z += w4.z*z3.z; c3.w += w4.w*z3.w;
            }
            const int mm = l >> 5;
            float u0 = (c0.x+c0.y+c0.z+c0.w + tbv) * a2loc[(b0+0)*2 + mm];
            float u1 = (c1.x+c1.y+c1.z+c1.w + tbv) * a2loc[(b0+1)*2 + mm];
            float u2 = (c2.x+c2.y+c2.z+c2.w + tbv) * a2loc[(b0+2)*2 + mm];
            float u3 = (c3.x+c3.y+c3.z+c3.w + tbv) * a2loc[(b0+3)*2 + mm];
            u0 += __shfl_xor(u0, 32);
            u1 += __shfl_xor(u1, 32);
            u2 += __shfl_xor(u2, 32);
            u3 += __shfl_xor(u3, 32);
            if (l < 32){
                int eb = q*32 + l;
                astore(&PD[(mh*32 + b0+0)*256 + eb], u0);
                astore(&PD[(mh*32 + b0+1)*256 + eb], u1);
                astore(&PD[(mh*32 + b0+2)*256 + eb], u2);
                astore(&PD[(mh*32 + b0+3)*256 + eb], u3);
            }
        }
        gen++; gbar(bar, gen);            // PD visible (LLC)
    }
}

// ---------------- vocab: bf16 MFMA logits + streaming sumexp + target ----------
__device__ __forceinline__ bf16x8 pack8f(const float* __restrict__ src){
    bf16x8 r;
    #pragma unroll
    for (int j = 0; j < 8; ++j) r[j] = (short)f2bf_bits(src[j]);
    return r;
}

template<bool VB>
__global__ __launch_bounds__(256, 1) void k_vocab(const unsigned short* __restrict__ vb,
                                                  const float* __restrict__ vwf,
                                                  const float* __restrict__ vbias,
                                                  const unsigned short* __restrict__ zsb,
                                                  const int* __restrict__ y,
                                                  float* __restrict__ pS,
                                                  float* __restrict__ pT,
                                                  int* __restrict__ bar)
{
    const int rowblk = blockIdx.x;   // 0..63  (64 rows each)
    const int split  = blockIdx.y;   // 0..3   (8000 vocab cols each)
    const int t = threadIdx.x;
    const int wave = t >> 6, lane = t & 63;
    const int kg = lane >> 4, nl = lane & 15;
    const int is64 = bar[136];

    __shared__ float psum_l[4][64];
    __shared__ float ptarg_l[4][64];
    __shared__ float chk[1];

    bf16x8 afr[4][8];
    #pragma unroll
    for (int mt = 0; mt < 4; ++mt)
        #pragma unroll
        for (int kk = 0; kk < 8; ++kk)
            afr[mt][kk] = *(const bf16x8*)&zsb[(size_t)(rowblk*64 + mt*16 + nl) * EE + kk*32 + kg*8];

    int tg[4][4];
    #pragma unroll
    for (int mt = 0; mt < 4; ++mt)
        #pragma unroll
        for (int i = 0; i < 4; ++i){
            int rg = rowblk*64 + mt*16 + kg*4 + i;
            tg[mt][i] = is64 ? y[2*rg] : y[rg];
        }

    float sums[4][4]; float targ[4][4];
    #pragma unroll
    for (int mt = 0; mt < 4; ++mt)
        #pragma unroll
        for (int i = 0; i < 4; ++i){ sums[mt][i] = 0.f; targ[mt][i] = 0.f; }

    for (int tile = wave; tile < 500; tile += 4){
        int n = split*8000 + tile*16 + nl;
        f32x4 acc[4];
        #pragma unroll
        for (int mt = 0; mt < 4; ++mt) acc[mt] = (f32x4){0.f,0.f,0.f,0.f};
        #pragma unroll
        for (int kk = 0; kk < 8; ++kk){
            bf16x8 bfr;
            if (VB) bfr = *(const bf16x8*)&vb[(size_t)n * EE + kk*32 + kg*8];
            else    bfr = pack8f(&vwf[(size_t)n * EE + kk*32 + kg*8]);
            #pragma unroll
            for (int mt = 0; mt < 4; ++mt)
                acc[mt] = __builtin_amdgcn_mfma_f32_16x16x32_bf16(afr[mt][kk], bfr, acc[mt], 0, 0, 0);
        }
        float bias = vbias[n];
        if (rowblk == 0 && split == 0 && t == 0 && tile == 0)
            chk[0] = acc[0][0] + bias;
        #pragma unroll
        for (int mt = 0; mt < 4; ++mt)
            #pragma unroll
            for (int i = 0; i < 4; ++i){
                float v = acc[mt][i] + bias;
                sums[mt][i] += expf(v);
                if (n == tg[mt][i]) targ[mt][i] += v;
            }
    }

    #pragma unroll
    for (int mt = 0; mt < 4; ++mt)
        #pragma unroll
        for (int i = 0; i < 4; ++i){
            float sv = sums[mt][i], tv = targ[mt][i];
            #pragma unroll
            for (int msk = 1; msk < 16; msk <<= 1){ sv += __shfl_xor(sv, msk); tv += __shfl_xor(tv, msk); }
            if (nl == 0){ int row = mt*16 + kg*4 + i; psum_l[wave][row] = sv; ptarg_l[wave][row] = tv; }
        }
    __syncthreads();
    if (t < 64){
        float sv = psum_l[0][t] + psum_l[1][t] + psum_l[2][t] + psum_l[3][t];
        float tv = ptarg_l[0][t] + ptarg_l[1][t] + ptarg_l[2][t] + ptarg_l[3][t];
        int r = rowblk*64 + t;
        pS[(size_t)split*ROWS + r] = sv;
        pT[(size_t)split*ROWS + r] = tv;
    }

    if (rowblk == 0 && split == 0 && t == 0){
        float s = 0.f;
        for (int k = 0; k < EE; ++k){
            float a = bf2f(zsb[k]);
            float w = VB ? bf2f(vb[k]) : bf2f(f2bf_bits(vwf[k]));
            s += a * w;
        }
        s += vbias[0];
        if (fabsf(s - chk[0]) > 0.02f) bar[133] = 1;
    }
}

__global__ __launch_bounds__(256) void k_final(const float* __restrict__ pS,
                                               const float* __restrict__ pT,
                                               const int* __restrict__ bar,
                                               float* __restrict__ outp)
{
    int r = blockIdx.x * 256 + threadIdx.x;
    float s = 0.f, g = 0.f;
    #pragma unroll
    for (int i = 0; i < VSPLIT; ++i){ s += pS[(size_t)i*ROWS + r]; g += pT[(size_t)i*ROWS + r]; }
    float v = g - logf(s);
    if (bar[132] != 0) v = 4000.0f;    // barrier timeout sentinel
    if (bar[133] != 0) v = 5000.0f;    // MFMA layout mismatch sentinel
    outp[r] = v;
}

extern "C" void kernel_launch(void* const* d_in, const int* in_sizes, int n_in,
                              void* d_out, int out_size, void* d_ws, size_t ws_size,
                              hipStream_t stream)
{
    (void)out_size;
    const float* latent   = (const float*)d_in[0];
    const float* trans_w  = (const float*)d_in[1];
    const float* trans_b  = (const float*)d_in[2];
    const float* anchor_w = (const float*)d_in[3];
    const float* anchor_b = (const float*)d_in[4];
    const float* vocab_w  = (const float*)d_in[5];
    const float* vocab_b  = (const float*)d_in[6];
    const int*   zi       = (const int*)d_in[7];
    const int*   y        = (const int*)d_in[8];

    float* outp = (float*)d_out;

    if (ws_size < (size_t)WS_REQ){ k_sentinel<<<16, 256, 0, stream>>>(outp, 2000.0f); return; }
    {
        bool ok = (n_in >= 9)
               && in_sizes[0] == 67108864 && in_sizes[1] == 1048576
               && in_sizes[2] == 4096     && in_sizes[3] == 4096
               && in_sizes[4] == 16       && in_sizes[5] == 8192000
               && in_sizes[6] == 32000
               && (in_sizes[7] == 32   || in_sizes[7] == 64)
               && (in_sizes[8] == 4096 || in_sizes[8] == 8192);
        if (!ok){ k_sentinel<<<16, 256, 0, stream>>>(outp, 2100.0f); return; }
    }

    char* ws = (char*)d_ws;
    unsigned short* zsb = (unsigned short*)(ws + OFF_ZSB);
    float* pS  = (float*)(ws + OFF_PS);
    float* pT  = (float*)(ws + OFF_PT);
    float* ZN  = (float*)(ws + OFF_ZN);
    float* A2  = (float*)(ws + OFF_A2);
    int*   bar = (int*)(ws + OFF_BAR);
    float* PD  = (float*)(ws + OFF_PD);
    unsigned short* vbu = (unsigned short*)(ws + OFF_VB);

    const bool use_vb = ws_size >= (size_t)OFF_VB + (size_t)VB_BYTES;

    k_prep<<<1, 256, 0, stream>>>(zi, bar);
    if (use_vb)
        k_cvt<<<GG*EE/1024, 256, 0, stream>>>(vocab_w, vbu);

    k_rnn<<<NWGR, 512, 0, stream>>>(latent, zi, anchor_w, anchor_b,
                                    trans_w, trans_b, zsb, ZN, PD, A2, bar);

    if (use_vb)
        k_vocab<true><<<dim3(64, VSPLIT), 256, 0, stream>>>(vbu, nullptr, vocab_b,
                                                            zsb, y, pS, pT, bar);
    else
        k_vocab<false><<<dim3(64, VSPLIT), 256, 0, stream>>>(nullptr, vocab_w, vocab_b,
                                                             zsb, y, pS, pT, bar);

    k_final<<<16, 256, 0, stream>>>(pS, pT, bar, outp);
}

// Round 13
// 2059.959 us; speedup vs baseline: 5.2063x; 1.1217x over previous
//
#include <hip/hip_runtime.h>

#define EE 256
#define GG 32000
#define NSTEP 128
#define ROWS 4096
#define VSPLIT 4
#define NWGR 64

typedef __attribute__((ext_vector_type(8))) short bf16x8;
typedef __attribute__((ext_vector_type(4))) float f32x4;

// ---------- workspace layout (bytes) ----------
#define OFF_ZSB  0u                      // bf16 zs 4096x256 = 2 MB
#define OFF_PS   2097152u                // f32 4x4096 = 64 KB
#define OFF_PT   (OFF_PS + 65536u)       // 64 KB
#define OFF_ZNB  (OFF_PT + 65536u)       // u32 2 planes x 32 x 128 = 32 KB
#define OFF_A2   (OFF_ZNB + 32768u)      // 4 KB
#define OFF_BAR  (OFF_A2 + 4096u)        // 4 KB ints
#define OFF_PD   (OFF_BAR + 4096u)       // f32 16x32x256 = 512 KB
#define WS_REQ   (OFF_PD + 524288u)      // 2,793,472 B (< confirmed 4,460,544)
#define OFF_VB   WS_REQ                  // optional bf16 vocab 16,384,000 B
#define VB_BYTES 16384000u

// bar int slots: flags[0..63], dead@132, mfmachk@133, is64@136

__device__ __forceinline__ float wredf(float v){
    #pragma unroll
    for (int m = 1; m < 64; m <<= 1) v += __shfl_xor(v, m);
    return v;
}
__device__ __forceinline__ unsigned short f2bf_bits(float f){
    unsigned int u = __float_as_uint(f);
    unsigned int lsb = (u >> 16) & 1u;
    u += 0x7fffu + lsb;
    return (unsigned short)(u >> 16);
}
__device__ __forceinline__ float bf2f(unsigned short u){
    return __uint_as_float(((unsigned int)u) << 16);
}
__device__ __forceinline__ float aload(const float* p){
    return __hip_atomic_load(p, __ATOMIC_RELAXED, __HIP_MEMORY_SCOPE_AGENT);
}
__device__ __forceinline__ void astore(float* p, float v){
    __hip_atomic_store(p, v, __ATOMIC_RELAXED, __HIP_MEMORY_SCOPE_AGENT);
}
__device__ __forceinline__ unsigned aloadu(const unsigned* p){
    return __hip_atomic_load(p, __ATOMIC_RELAXED, __HIP_MEMORY_SCOPE_AGENT);
}
__device__ __forceinline__ void astoreu(unsigned* p, unsigned v){
    __hip_atomic_store(p, v, __ATOMIC_RELAXED, __HIP_MEMORY_SCOPE_AGENT);
}
// XOR swizzle within a 512-byte row (8 x 16B slots), breaks row-stride conflicts
__device__ __forceinline__ int swz(int row, int kbyte){
    return row*512 + (kbyte ^ ((row & 7) << 4));
}

__global__ __launch_bounds__(256) void k_sentinel(float* __restrict__ outp, float val){
    int r = blockIdx.x * 256 + threadIdx.x;
    outp[r] = val;
}

__global__ void k_prep(const int* __restrict__ zi, int* __restrict__ bar){
    int t = threadIdx.x;
    bar[t] = 0;            // re-zeroed EVERY replay
    __syncthreads();
    if (t == 0){
        bool odd_zero = true, even_ok = true;
        for (int i = 0; i < 16; ++i){
            int lo = zi[2*i], hi = zi[2*i+1];
            if (hi != 0) odd_zero = false;
            if (lo < 0 || lo >= 8192) even_ok = false;
        }
        bar[136] = (odd_zero && even_ok) ? 1 : 0;
    }
}

// ---------------- vocab f32 -> bf16 (RNE, matches pack8f) ----------------
__global__ __launch_bounds__(256) void k_cvt(const float* __restrict__ in,
                                             unsigned short* __restrict__ outp)
{
    int i = (blockIdx.x * 256 + threadIdx.x) * 4;
    float4 v = *(const float4*)&in[i];
    ushort4 o;
    o.x = f2bf_bits(v.x); o.y = f2bf_bits(v.y);
    o.z = f2bf_bits(v.z); o.w = f2bf_bits(v.w);
    *(ushort4*)&outp[i] = o;
}

// ---- grid barrier: all-to-all flag poll (one LLC propagation) ----
__device__ __forceinline__ void gbar(int* __restrict__ bar, int gen){
    __syncthreads();
    const int t = threadIdx.x, wg = blockIdx.x;
    if (t == 0)
        __hip_atomic_store(&bar[wg], gen, __ATOMIC_RELAXED, __HIP_MEMORY_SCOPE_AGENT);
    if (t < NWGR){
        int spins = 0;
        while (__hip_atomic_load(&bar[t], __ATOMIC_RELAXED, __HIP_MEMORY_SCOPE_AGENT) < gen){
            __builtin_amdgcn_s_sleep(1);
            if (++spins > 2000000){
                __hip_atomic_store(&bar[132], 1, __ATOMIC_RELAXED, __HIP_MEMORY_SCOPE_AGENT);
                break;
            }
            if ((spins & 2047) == 0 &&
                __hip_atomic_load(&bar[132], __ATOMIC_RELAXED, __HIP_MEMORY_SCOPE_AGENT) != 0)
                break;
        }
    }
    __syncthreads();
    __builtin_amdgcn_sched_barrier(0);
}

// ---------------- fused recurrence: 64 WGs, MFMA phase-D ----------------
// WG w: mh = w>>3 (m-pair), q = w&7 (e-32-slice).
// W slice (2 m x 32 e x 256 k) in LDS as hi/lo bf16 planes (64 KB).
// Per step: U[e][b] via 16x16x32 bf16 MFMA, 3-term hi/lo split (~f32 accuracy):
// wave wv -> (m = wv>>2, e-tile = (wv>>1)&1, b-tile = wv&1), 8 k-steps.
__global__ __launch_bounds__(512, 1) void k_rnn(const float* __restrict__ latent,
                                                const int* __restrict__ zi,
                                                const float* __restrict__ anchor_w,
                                                const float* __restrict__ anchor_b,
                                                const float* __restrict__ trans_w,
                                                const float* __restrict__ trans_b,
                                                unsigned short* __restrict__ zsb,
                                                unsigned* __restrict__ ZNB,
                                                float* __restrict__ PD,
                                                float* __restrict__ A2,
                                                int* __restrict__ bar)
{
    __shared__ __align__(16) unsigned char WbRaw[2*64*512];   // 64 KB hi/lo planes
    __shared__ __align__(16) unsigned char ZNbRaw[2*32*512];  // 32 KB hi/lo planes
    __shared__ float xk_l[16][260];
    __shared__ float xv_l[16][260];
    __shared__ float zl[256];
    __shared__ float a2l[64];        // [b][m]
    __shared__ float tbl[2][32];     // [m][e_loc]
    __shared__ float l1s[16], l2s[16], ab_l[16], rbuf[8];

    const int wg = blockIdx.x, t = threadIdx.x;
    const int mh = wg >> 3, q = wg & 7;
    const int is64 = bar[136];
    const int lane = t & 63, wv = t >> 6;
    const int kg = lane >> 4, nl = lane & 15;

    // ---- stage W slice once: f32 -> hi/lo bf16, swizzled ----
    for (int idx = t; idx < 4096; idx += 512){
        int r = idx >> 6, c = idx & 63;                 // r: mm*32+e_loc, c: 4-float chunk
        int grow = (2*mh + (r >> 5))*256 + q*32 + (r & 31);
        float4 w = *(const float4*)&trans_w[(size_t)grow*256 + c*4];
        unsigned short h0 = f2bf_bits(w.x), h1 = f2bf_bits(w.y);
        unsigned short h2 = f2bf_bits(w.z), h3 = f2bf_bits(w.w);
        unsigned short l0 = f2bf_bits(w.x - bf2f(h0)), l1 = f2bf_bits(w.y - bf2f(h1));
        unsigned short l2 = f2bf_bits(w.z - bf2f(h2)), l3 = f2bf_bits(w.w - bf2f(h3));
        int off = swz(r, c*8);
        *(unsigned*)&WbRaw[off]     = (unsigned)h0 | ((unsigned)h1 << 16);
        *(unsigned*)&WbRaw[off + 4] = (unsigned)h2 | ((unsigned)h3 << 16);
        *(unsigned*)&WbRaw[64*512 + off]     = (unsigned)l0 | ((unsigned)l1 << 16);
        *(unsigned*)&WbRaw[64*512 + off + 4] = (unsigned)l2 | ((unsigned)l3 << 16);
    }
    if (t < 64) tbl[t >> 5][t & 31] = trans_b[(2*mh + (t >> 5))*256 + q*32 + (t & 31)];

    const bool isb = (wg < 32);
    const int b = wg;
    const float* base = nullptr;
    float zn_r = 0.f, em_r = 0.f;
    if (isb){
        int zb = is64 ? zi[2*b] : zi[b];
        base = latent + (size_t)zb * 8192;   // xk=base[0:4096]*100, xv=base[4096:]*100
        for (int i = t; i < 4096; i += 512){
            int s = i >> 8, c = i & 255;
            xk_l[s][c] = base[i];
            xv_l[s][c] = base[4096 + i];
        }
        if (t < 16) ab_l[t] = anchor_b[t];
    }
    __syncthreads();

    int gen = 0;
    for (int stp = 0; stp < NSTEP; ++stp){
        // ---- phase 1 (batch WGs) ----
        if (isb){
            float zv = 0.f;
            if (t < 256){
                if (stp == 0) zv = base[t];
                else {
                    float dz = 0.f;
                    #pragma unroll
                    for (int g = 0; g < 16; ++g) dz += aload(&PD[(g*32 + b)*256 + t]);
                    zv = zn_r + em_r + dz;
                }
                float s1 = wredf(zv), s2 = wredf(zv*zv);
                if ((t & 63) == 0){ rbuf[t>>6] = s1; rbuf[4 + (t>>6)] = s2; }
            }
            __syncthreads();
            if (t < 256){
                float tot1 = rbuf[0]+rbuf[1]+rbuf[2]+rbuf[3];
                float tot2 = rbuf[4]+rbuf[5]+rbuf[6]+rbuf[7];
                float mean = tot1 * (1.0f/EE);
                float var  = (tot2 - (float)EE*mean*mean) * (1.0f/(EE-1));
                var = fmaxf(var, 0.f);
                float sc = 0.113f / (1e-5f + sqrtf(var));
                zn_r = zv * sc;
                zl[t] = zn_r;
                // publish zn as packed hi/lo bf16 (LLC)
                unsigned short zh = f2bf_bits(zn_r);
                unsigned short zlo = f2bf_bits(zn_r - bf2f(zh));
                unsigned ohi = (unsigned)__shfl_xor((int)(unsigned)zh, 1);
                unsigned olo = (unsigned)__shfl_xor((int)(unsigned)zlo, 1);
                if (!(t & 1)){
                    astoreu(&ZNB[b*128 + (t >> 1)],        (unsigned)zh  | (ohi << 16));
                    astoreu(&ZNB[4096 + b*128 + (t >> 1)], (unsigned)zlo | (olo << 16));
                }
            }
            __syncthreads();
            if (t < 256){
                int sidx = t >> 4, L = t & 15;
                const float* aws = anchor_w + sidx*EE;
                float p1 = 0.f, p2 = 0.f;
                #pragma unroll
                for (int c = 0; c < 16; ++c){
                    int k = L*16 + c;
                    float z = zl[k];
                    p1 += z * xk_l[sidx][k];
                    p2 += z * aws[k];
                }
                #pragma unroll
                for (int mm = 1; mm < 16; mm <<= 1){ p1 += __shfl_xor(p1, mm); p2 += __shfl_xor(p2, mm); }
                if (L == 0){ l1s[sidx] = p1 * 100.0f; l2s[sidx] = p2 + ab_l[sidx]; }
            }
            __syncthreads();
            if (t < 256){
                float mx1 = -1e30f, mx2 = -1e30f;
                #pragma unroll
                for (int s = 0; s < 16; ++s){ mx1 = fmaxf(mx1, l1s[s]); mx2 = fmaxf(mx2, l2s[s]); }
                float att[16]; float sum1 = 0.f, sum2 = 0.f;
                #pragma unroll
                for (int s = 0; s < 16; ++s){
                    att[s] = expf(l1s[s] - mx1); sum1 += att[s];
                    sum2  += expf(l2s[s] - mx2);
                }
                float inv1 = 1.0f / sum1;
                if (t < 16) astore(&A2[b*16 + t], expf(l2s[t] - mx2) / sum2);
                float em = 0.f;
                #pragma unroll
                for (int s = 0; s < 16; ++s) em += (att[s] * inv1) * xv_l[s][t];
                em *= 100.0f;
                em_r = em;
                zsb[((size_t)b*NSTEP + stp)*EE + t] = f2bf_bits(em);
            }
        }
        if (stp == NSTEP-1) break;
        gen++; gbar(bar, gen);            // ZNB/A2 visible (LLC)

        // ---- phase D: stage zn hi/lo to LDS, MFMA, PD stores ----
        for (int i = t; i < 8192; i += 512){
            int p = i >> 12, rr = (i >> 7) & 31, d = i & 127;
            unsigned v = aloadu(&ZNB[i]);
            *(unsigned*)&ZNbRaw[p*(32*512) + swz(rr, d*4)] = v;
        }
        if (t < 64) a2l[t] = aload(&A2[(t >> 1)*16 + 2*mh + (t & 1)]);
        __syncthreads();
        {
            const int m = wv >> 2, et = (wv >> 1) & 1, bt = wv & 1;
            const int arow = m*32 + et*16 + nl;
            const int brow = bt*16 + nl;
            f32x4 acc = {0.f, 0.f, 0.f, 0.f};
            #pragma unroll
            for (int kk = 0; kk < 8; ++kk){
                int kb = kk*64 + kg*16;
                bf16x8 ah = *(const bf16x8*)&WbRaw[swz(arow, kb)];
                bf16x8 al = *(const bf16x8*)&WbRaw[64*512 + swz(arow, kb)];
                bf16x8 bh = *(const bf16x8*)&ZNbRaw[swz(brow, kb)];
                bf16x8 bl = *(const bf16x8*)&ZNbRaw[32*512 + swz(brow, kb)];
                acc = __builtin_amdgcn_mfma_f32_16x16x32_bf16(ah, bh, acc, 0, 0, 0);
                acc = __builtin_amdgcn_mfma_f32_16x16x32_bf16(ah, bl, acc, 0, 0, 0);
                acc = __builtin_amdgcn_mfma_f32_16x16x32_bf16(al, bh, acc, 0, 0, 0);
            }
            float a2v = a2l[brow*2 + m];
            #pragma unroll
            for (int i = 0; i < 4; ++i){
                int e_loc = et*16 + kg*4 + i;           // C/D: row = kg*4+i, col = nl (m89)
                float u = acc[i] + tbl[m][e_loc];
                astore(&PD[(((mh << 1) + m)*32 + brow)*256 + q*32 + e_loc], a2v * u);
            }
        }
        gen++; gbar(bar, gen);            // PD visible (LLC)
    }
}

// ---------------- vocab: bf16 MFMA logits + streaming sumexp + target ----------
__device__ __forceinline__ bf16x8 pack8f(const float* __restrict__ src){
    bf16x8 r;
    #pragma unroll
    for (int j = 0; j < 8; ++j) r[j] = (short)f2bf_bits(src[j]);
    return r;
}

template<bool VB>
__global__ __launch_bounds__(256, 1) void k_vocab(const unsigned short* __restrict__ vb,
                                                  const float* __restrict__ vwf,
                                                  const float* __restrict__ vbias,
                                                  const unsigned short* __restrict__ zsb,
                                                  const int* __restrict__ y,
                                                  float* __restrict__ pS,
                                                  float* __restrict__ pT,
                                                  int* __restrict__ bar)
{
    const int rowblk = blockIdx.x;
    const int split  = blockIdx.y;
    const int t = threadIdx.x;
    const int wave = t >> 6, lane = t & 63;
    const int kg = lane >> 4, nl = lane & 15;
    const int is64 = bar[136];

    __shared__ float psum_l[4][64];
    __shared__ float ptarg_l[4][64];
    __shared__ float chk[1];

    bf16x8 afr[4][8];
    #pragma unroll
    for (int mt = 0; mt < 4; ++mt)
        #pragma unroll
        for (int kk = 0; kk < 8; ++kk)
            afr[mt][kk] = *(const bf16x8*)&zsb[(size_t)(rowblk*64 + mt*16 + nl) * EE + kk*32 + kg*8];

    int tg[4][4];
    #pragma unroll
    for (int mt = 0; mt < 4; ++mt)
        #pragma unroll
        for (int i = 0; i < 4; ++i){
            int rg = rowblk*64 + mt*16 + kg*4 + i;
            tg[mt][i] = is64 ? y[2*rg] : y[rg];
        }

    float sums[4][4]; float targ[4][4];
    #pragma unroll
    for (int mt = 0; mt < 4; ++mt)
        #pragma unroll
        for (int i = 0; i < 4; ++i){ sums[mt][i] = 0.f; targ[mt][i] = 0.f; }

    for (int tile = wave; tile < 500; tile += 4){
        int n = split*8000 + tile*16 + nl;
        f32x4 acc[4];
        #pragma unroll
        for (int mt = 0; mt < 4; ++mt) acc[mt] = (f32x4){0.f,0.f,0.f,0.f};
        #pragma unroll
        for (int kk = 0; kk < 8; ++kk){
            bf16x8 bfr;
            if (VB) bfr = *(const bf16x8*)&vb[(size_t)n * EE + kk*32 + kg*8];
            else    bfr = pack8f(&vwf[(size_t)n * EE + kk*32 + kg*8]);
            #pragma unroll
            for (int mt = 0; mt < 4; ++mt)
                acc[mt] = __builtin_amdgcn_mfma_f32_16x16x32_bf16(afr[mt][kk], bfr, acc[mt], 0, 0, 0);
        }
        float bias = vbias[n];
        if (rowblk == 0 && split == 0 && t == 0 && tile == 0)
            chk[0] = acc[0][0] + bias;
        #pragma unroll
        for (int mt = 0; mt < 4; ++mt)
            #pragma unroll
            for (int i = 0; i < 4; ++i){
                float v = acc[mt][i] + bias;
                sums[mt][i] += expf(v);
                if (n == tg[mt][i]) targ[mt][i] += v;
            }
    }

    #pragma unroll
    for (int mt = 0; mt < 4; ++mt)
        #pragma unroll
        for (int i = 0; i < 4; ++i){
            float sv = sums[mt][i], tv = targ[mt][i];
            #pragma unroll
            for (int msk = 1; msk < 16; msk <<= 1){ sv += __shfl_xor(sv, msk); tv += __shfl_xor(tv, msk); }
            if (nl == 0){ int row = mt*16 + kg*4 + i; psum_l[wave][row] = sv; ptarg_l[wave][row] = tv; }
        }
    __syncthreads();
    if (t < 64){
        float sv = psum_l[0][t] + psum_l[1][t] + psum_l[2][t] + psum_l[3][t];
        float tv = ptarg_l[0][t] + ptarg_l[1][t] + ptarg_l[2][t] + ptarg_l[3][t];
        int r = rowblk*64 + t;
        pS[(size_t)split*ROWS + r] = sv;
        pT[(size_t)split*ROWS + r] = tv;
    }

    if (rowblk == 0 && split == 0 && t == 0){
        float s = 0.f;
        for (int k = 0; k < EE; ++k){
            float a = bf2f(zsb[k]);
            float w = VB ? bf2f(vb[k]) : bf2f(f2bf_bits(vwf[k]));
            s += a * w;
        }
        s += vbias[0];
        if (fabsf(s - chk[0]) > 0.02f) bar[133] = 1;
    }
}

__global__ __launch_bounds__(256) void k_final(const float* __restrict__ pS,
                                               const float* __restrict__ pT,
                                               const int* __restrict__ bar,
                                               float* __restrict__ outp)
{
    int r = blockIdx.x * 256 + threadIdx.x;
    float s = 0.f, g = 0.f;
    #pragma unroll
    for (int i = 0; i < VSPLIT; ++i){ s += pS[(size_t)i*ROWS + r]; g += pT[(size_t)i*ROWS + r]; }
    float v = g - logf(s);
    if (bar[132] != 0) v = 4000.0f;    // barrier timeout sentinel
    if (bar[133] != 0) v = 5000.0f;    // MFMA layout mismatch sentinel
    outp[r] = v;
}

extern "C" void kernel_launch(void* const* d_in, const int* in_sizes, int n_in,
                              void* d_out, int out_size, void* d_ws, size_t ws_size,
                              hipStream_t stream)
{
    (void)out_size;
    const float* latent   = (const float*)d_in[0];
    const float* trans_w  = (const float*)d_in[1];
    const float* trans_b  = (const float*)d_in[2];
    const float* anchor_w = (const float*)d_in[3];
    const float* anchor_b = (const float*)d_in[4];
    const float* vocab_w  = (const float*)d_in[5];
    const float* vocab_b  = (const float*)d_in[6];
    const int*   zi       = (const int*)d_in[7];
    const int*   y        = (const int*)d_in[8];

    float* outp = (float*)d_out;

    if (ws_size < (size_t)WS_REQ){ k_sentinel<<<16, 256, 0, stream>>>(outp, 2000.0f); return; }
    {
        bool ok = (n_in >= 9)
               && in_sizes[0] == 67108864 && in_sizes[1] == 1048576
               && in_sizes[2] == 4096     && in_sizes[3] == 4096
               && in_sizes[4] == 16       && in_sizes[5] == 8192000
               && in_sizes[6] == 32000
               && (in_sizes[7] == 32   || in_sizes[7] == 64)
               && (in_sizes[8] == 4096 || in_sizes[8] == 8192);
        if (!ok){ k_sentinel<<<16, 256, 0, stream>>>(outp, 2100.0f); return; }
    }

    char* ws = (char*)d_ws;
    unsigned short* zsb = (unsigned short*)(ws + OFF_ZSB);
    float*    pS  = (float*)(ws + OFF_PS);
    float*    pT  = (float*)(ws + OFF_PT);
    unsigned* ZNB = (unsigned*)(ws + OFF_ZNB);
    float*    A2  = (float*)(ws + OFF_A2);
    int*      bar = (int*)(ws + OFF_BAR);
    float*    PD  = (float*)(ws + OFF_PD);
    unsigned short* vbu = (unsigned short*)(ws + OFF_VB);

    const bool use_vb = ws_size >= (size_t)OFF_VB + (size_t)VB_BYTES;

    k_prep<<<1, 256, 0, stream>>>(zi, bar);
    if (use_vb)
        k_cvt<<<GG*EE/1024, 256, 0, stream>>>(vocab_w, vbu);

    k_rnn<<<NWGR, 512, 0, stream>>>(latent, zi, anchor_w, anchor_b,
                                    trans_w, trans_b, zsb, ZNB, PD, A2, bar);

    if (use_vb)
        k_vocab<true><<<dim3(64, VSPLIT), 256, 0, stream>>>(vbu, nullptr, vocab_b,
                                                            zsb, y, pS, pT, bar);
    else
        k_vocab<false><<<dim3(64, VSPLIT), 256, 0, stream>>>(nullptr, vocab_w, vocab_b,
                                                             zsb, y, pS, pT, bar);

    k_final<<<16, 256, 0, stream>>>(pS, pT, bar, outp);
}

// Round 14
// 1854.033 us; speedup vs baseline: 5.7845x; 1.1111x over previous
//
#include <hip/hip_runtime.h>

#define EE 256
#define GG 32000
#define NSTEP 128
#define ROWS 4096
#define VSPLIT 4
#define NWGP 32
#define NWGD 64
#define NWGR (NWGP + NWGD)

typedef __attribute__((ext_vector_type(8))) short bf16x8;
typedef __attribute__((ext_vector_type(4))) float f32x4;

// ---------- workspace layout (bytes) ----------
#define OFF_ZSB  0u                      // bf16 zs 4096x256 = 2 MB
#define OFF_PS   2097152u                // f32 4x4096 = 64 KB
#define OFF_PT   (OFF_PS + 65536u)       // 64 KB
#define OFF_ZNB  (OFF_PT + 65536u)       // u32 2 planes x 32 x 128 = 32 KB
#define OFF_BAR  (OFF_ZNB + 32768u)      // 4 KB ints
#define OFF_PD   (OFF_BAR + 4096u)       // f32 16x32x256 = 512 KB
#define WS_REQ   (OFF_PD + 524288u)      // 2,789,376 B (< confirmed 4,460,544)
#define OFF_VB   WS_REQ                  // optional bf16 vocab 16,384,000 B
#define VB_BYTES 16384000u

// bar int slots: flagsA[0..31] (P1 arrive), flagsB[64..127] (D arrive),
// dead@132, mfmachk@133, is64@136

__device__ __forceinline__ float wredf(float v){
    #pragma unroll
    for (int m = 1; m < 64; m <<= 1) v += __shfl_xor(v, m);
    return v;
}
__device__ __forceinline__ unsigned short f2bf_bits(float f){
    unsigned int u = __float_as_uint(f);
    unsigned int lsb = (u >> 16) & 1u;
    u += 0x7fffu + lsb;
    return (unsigned short)(u >> 16);
}
__device__ __forceinline__ float bf2f(unsigned short u){
    return __uint_as_float(((unsigned int)u) << 16);
}
__device__ __forceinline__ float aload(const float* p){
    return __hip_atomic_load(p, __ATOMIC_RELAXED, __HIP_MEMORY_SCOPE_AGENT);
}
__device__ __forceinline__ void astore(float* p, float v){
    __hip_atomic_store(p, v, __ATOMIC_RELAXED, __HIP_MEMORY_SCOPE_AGENT);
}
__device__ __forceinline__ unsigned aloadu(const unsigned* p){
    return __hip_atomic_load(p, __ATOMIC_RELAXED, __HIP_MEMORY_SCOPE_AGENT);
}
__device__ __forceinline__ void astoreu(unsigned* p, unsigned v){
    __hip_atomic_store(p, v, __ATOMIC_RELAXED, __HIP_MEMORY_SCOPE_AGENT);
}
__device__ __forceinline__ int swz(int row, int kbyte){
    return row*512 + (kbyte ^ ((row & 7) << 4));
}
// poll one flag until >= gen (with timeout -> dead)
__device__ __forceinline__ void pollflag(int* bar, int idx, int gen){
    int spins = 0;
    while (__hip_atomic_load(&bar[idx], __ATOMIC_RELAXED, __HIP_MEMORY_SCOPE_AGENT) < gen){
        __builtin_amdgcn_s_sleep(1);
        if (++spins > 2000000){
            __hip_atomic_store(&bar[132], 1, __ATOMIC_RELAXED, __HIP_MEMORY_SCOPE_AGENT);
            break;
        }
        if ((spins & 2047) == 0 &&
            __hip_atomic_load(&bar[132], __ATOMIC_RELAXED, __HIP_MEMORY_SCOPE_AGENT) != 0)
            break;
    }
}

__global__ __launch_bounds__(256) void k_sentinel(float* __restrict__ outp, float val){
    int r = blockIdx.x * 256 + threadIdx.x;
    outp[r] = val;
}

__global__ void k_prep(const int* __restrict__ zi, int* __restrict__ bar){
    int t = threadIdx.x;
    bar[t] = 0;            // re-zeroed EVERY replay
    __syncthreads();
    if (t == 0){
        bool odd_zero = true, even_ok = true;
        for (int i = 0; i < 16; ++i){
            int lo = zi[2*i], hi = zi[2*i+1];
            if (hi != 0) odd_zero = false;
            if (lo < 0 || lo >= 8192) even_ok = false;
        }
        bar[136] = (odd_zero && even_ok) ? 1 : 0;
    }
}

// ---------------- vocab f32 -> bf16 (RNE, matches pack8f) ----------------
__global__ __launch_bounds__(256) void k_cvt(const float* __restrict__ in,
                                             unsigned short* __restrict__ outp)
{
    int i = (blockIdx.x * 256 + threadIdx.x) * 4;
    float4 v = *(const float4*)&in[i];
    ushort4 o;
    o.x = f2bf_bits(v.x); o.y = f2bf_bits(v.y);
    o.z = f2bf_bits(v.z); o.w = f2bf_bits(v.w);
    *(ushort4*)&outp[i] = o;
}

// ---------------- fused recurrence: 96 WGs, producer-consumer pipeline -------
// WGs 0..31  (P1, one per batch): gather a2-weighted PD -> z -> zn -> publish
//   ZNB -> flagA ; then OVERLAPPED tail: logits/softmax (a2 stays local)/emit.
// WGs 32..95 (D): wait flagsA -> stage ZNB -> hi/lo MFMA -> publish raw U
//   (W row . zn + tb, NO a2 scale) -> flagB.
__global__ __launch_bounds__(512, 1) void k_rnn(const float* __restrict__ latent,
                                                const int* __restrict__ zi,
                                                const float* __restrict__ anchor_w,
                                                const float* __restrict__ anchor_b,
                                                const float* __restrict__ trans_w,
                                                const float* __restrict__ trans_b,
                                                unsigned short* __restrict__ zsb,
                                                unsigned* __restrict__ ZNB,
                                                float* __restrict__ PD,
                                                int* __restrict__ bar)
{
    __shared__ __align__(16) unsigned char WbRaw[2*64*512];   // 64 KB (D)
    __shared__ __align__(16) unsigned char ZNbRaw[2*32*512];  // 32 KB (D)
    __shared__ float xk_l[16][260];                           // (P1)
    __shared__ float xv_l[16][260];
    __shared__ float zl[256];
    __shared__ float a2s[16];
    __shared__ float tbl[2][32];
    __shared__ float l1s[16], l2s[16], ab_l[16], rbuf[8];

    const int wg = blockIdx.x, t = threadIdx.x;
    const int is64 = bar[136];
    const int lane = t & 63, wv = t >> 6;
    const int kg = lane >> 4, nl = lane & 15;

    if (wg < NWGP){
        // ======================= P1 role (batch b) =======================
        const int b = wg;
        int zb = is64 ? zi[2*b] : zi[b];
        const float* base = latent + (size_t)zb * 8192;  // xk=base[0:4096]*100, xv=base[4096:]*100
        for (int i = t; i < 4096; i += 512){
            int s = i >> 8, c = i & 255;
            xk_l[s][c] = base[i];
            xv_l[s][c] = base[4096 + i];
        }
        if (t < 16) ab_l[t] = anchor_b[t];
        __syncthreads();

        float zn_r = 0.f, em_r = 0.f;
        for (int stp = 0; stp < NSTEP; ++stp){
            if (stp > 0){
                if (t < NWGD) pollflag(bar, 64 + t, stp);   // wait all D done
                __syncthreads();
                __builtin_amdgcn_sched_barrier(0);
            }
            // ---- head: z update + norm + publish zn ----
            float zv = 0.f;
            if (t < 256){
                if (stp == 0) zv = base[t];
                else {
                    float dz = 0.f;
                    #pragma unroll
                    for (int g = 0; g < 16; ++g)
                        dz += a2s[g] * aload(&PD[(g*32 + b)*256 + t]);
                    zv = zn_r + em_r + dz;
                }
                float s1 = wredf(zv), s2 = wredf(zv*zv);
                if ((t & 63) == 0){ rbuf[t>>6] = s1; rbuf[4 + (t>>6)] = s2; }
            }
            __syncthreads();
            if (t < 256){
                float tot1 = rbuf[0]+rbuf[1]+rbuf[2]+rbuf[3];
                float tot2 = rbuf[4]+rbuf[5]+rbuf[6]+rbuf[7];
                float mean = tot1 * (1.0f/EE);
                float var  = (tot2 - (float)EE*mean*mean) * (1.0f/(EE-1));
                var = fmaxf(var, 0.f);
                float sc = 0.113f / (1e-5f + sqrtf(var));
                zn_r = zv * sc;
                zl[t] = zn_r;
                if (stp < NSTEP-1){
                    unsigned short zh  = f2bf_bits(zn_r);
                    unsigned short zlo = f2bf_bits(zn_r - bf2f(zh));
                    unsigned ohi = (unsigned)__shfl_xor((int)(unsigned)zh, 1);
                    unsigned olo = (unsigned)__shfl_xor((int)(unsigned)zlo, 1);
                    if (!(t & 1)){
                        astoreu(&ZNB[b*128 + (t >> 1)],        (unsigned)zh  | (ohi << 16));
                        astoreu(&ZNB[4096 + b*128 + (t >> 1)], (unsigned)zlo | (olo << 16));
                    }
                }
            }
            __syncthreads();                     // drains ZNB stores (vmcnt)
            if (stp < NSTEP-1 && t == 0)
                __hip_atomic_store(&bar[b], stp + 1, __ATOMIC_RELAXED, __HIP_MEMORY_SCOPE_AGENT);

            // ---- tail (overlaps with D phase): logits/softmax/emit ----
            if (t < 256){
                int sidx = t >> 4, L = t & 15;
                const float* aws = anchor_w + sidx*EE;
                float p1 = 0.f, p2 = 0.f;
                #pragma unroll
                for (int c = 0; c < 16; ++c){
                    int k = L*16 + c;
                    float z = zl[k];
                    p1 += z * xk_l[sidx][k];
                    p2 += z * aws[k];
                }
                #pragma unroll
                for (int mm = 1; mm < 16; mm <<= 1){ p1 += __shfl_xor(p1, mm); p2 += __shfl_xor(p2, mm); }
                if (L == 0){ l1s[sidx] = p1 * 100.0f; l2s[sidx] = p2 + ab_l[sidx]; }
            }
            __syncthreads();
            if (t < 256){
                float mx1 = -1e30f, mx2 = -1e30f;
                #pragma unroll
                for (int s = 0; s < 16; ++s){ mx1 = fmaxf(mx1, l1s[s]); mx2 = fmaxf(mx2, l2s[s]); }
                float att[16]; float sum1 = 0.f, sum2 = 0.f;
                #pragma unroll
                for (int s = 0; s < 16; ++s){
                    att[s] = expf(l1s[s] - mx1); sum1 += att[s];
                    sum2  += expf(l2s[s] - mx2);
                }
                float inv1 = 1.0f / sum1;
                if (t < 16) a2s[t] = expf(l2s[t] - mx2) / sum2;   // stays local!
                float em = 0.f;
                #pragma unroll
                for (int s = 0; s < 16; ++s) em += (att[s] * inv1) * xv_l[s][t];
                em *= 100.0f;
                em_r = em;
                zsb[((size_t)b*NSTEP + stp)*EE + t] = f2bf_bits(em);
            }
            __syncthreads();                     // a2s ready for next gather
        }
    } else {
        // ======================= D role =======================
        const int d = wg - NWGP;
        const int mh = d >> 3, q = d & 7;

        for (int idx = t; idx < 4096; idx += 512){
            int r = idx >> 6, c = idx & 63;
            int grow = (2*mh + (r >> 5))*256 + q*32 + (r & 31);
            float4 w = *(const float4*)&trans_w[(size_t)grow*256 + c*4];
            unsigned short h0 = f2bf_bits(w.x), h1 = f2bf_bits(w.y);
            unsigned short h2 = f2bf_bits(w.z), h3 = f2bf_bits(w.w);
            unsigned short l0 = f2bf_bits(w.x - bf2f(h0)), l1 = f2bf_bits(w.y - bf2f(h1));
            unsigned short l2 = f2bf_bits(w.z - bf2f(h2)), l3 = f2bf_bits(w.w - bf2f(h3));
            int off = swz(r, c*8);
            *(unsigned*)&WbRaw[off]     = (unsigned)h0 | ((unsigned)h1 << 16);
            *(unsigned*)&WbRaw[off + 4] = (unsigned)h2 | ((unsigned)h3 << 16);
            *(unsigned*)&WbRaw[64*512 + off]     = (unsigned)l0 | ((unsigned)l1 << 16);
            *(unsigned*)&WbRaw[64*512 + off + 4] = (unsigned)l2 | ((unsigned)l3 << 16);
        }
        if (t < 64) tbl[t >> 5][t & 31] = trans_b[(2*mh + (t >> 5))*256 + q*32 + (t & 31)];
        __syncthreads();

        for (int k = 1; k < NSTEP; ++k){
            if (t < NWGP) pollflag(bar, t, k);      // wait all P1 published ZNB(k-1)
            __syncthreads();
            __builtin_amdgcn_sched_barrier(0);

            for (int i = t; i < 8192; i += 512){
                int p = i >> 12, rr = (i >> 7) & 31, dd = i & 127;
                unsigned v = aloadu(&ZNB[i]);
                *(unsigned*)&ZNbRaw[p*(32*512) + swz(rr, dd*4)] = v;
            }
            __syncthreads();
            {
                const int m = wv >> 2, et = (wv >> 1) & 1, bt = wv & 1;
                const int arow = m*32 + et*16 + nl;
                const int brow = bt*16 + nl;
                f32x4 acc = {0.f, 0.f, 0.f, 0.f};
                #pragma unroll
                for (int kk = 0; kk < 8; ++kk){
                    int kb = kk*64 + kg*16;
                    bf16x8 ah = *(const bf16x8*)&WbRaw[swz(arow, kb)];
                    bf16x8 al = *(const bf16x8*)&WbRaw[64*512 + swz(arow, kb)];
                    bf16x8 bh = *(const bf16x8*)&ZNbRaw[swz(brow, kb)];
                    bf16x8 bl = *(const bf16x8*)&ZNbRaw[32*512 + swz(brow, kb)];
                    acc = __builtin_amdgcn_mfma_f32_16x16x32_bf16(ah, bh, acc, 0, 0, 0);
                    acc = __builtin_amdgcn_mfma_f32_16x16x32_bf16(ah, bl, acc, 0, 0, 0);
                    acc = __builtin_amdgcn_mfma_f32_16x16x32_bf16(al, bh, acc, 0, 0, 0);
                }
                #pragma unroll
                for (int i = 0; i < 4; ++i){
                    int e_loc = et*16 + kg*4 + i;     // C/D: row=kg*4+i (e), col=nl (b)
                    float u = acc[i] + tbl[m][e_loc];
                    astore(&PD[(((mh << 1) + m)*32 + brow)*256 + q*32 + e_loc], u);
                }
            }
            __syncthreads();                          // drains PD stores
            if (t == 0)
                __hip_atomic_store(&bar[64 + d], k, __ATOMIC_RELAXED, __HIP_MEMORY_SCOPE_AGENT);
        }
    }
}

// ---------------- vocab: bf16 MFMA logits + streaming sumexp + target ----------
__device__ __forceinline__ bf16x8 pack8f(const float* __restrict__ src){
    bf16x8 r;
    #pragma unroll
    for (int j = 0; j < 8; ++j) r[j] = (short)f2bf_bits(src[j]);
    return r;
}

template<bool VB>
__global__ __launch_bounds__(256, 1) void k_vocab(const unsigned short* __restrict__ vb,
                                                  const float* __restrict__ vwf,
                                                  const float* __restrict__ vbias,
                                                  const unsigned short* __restrict__ zsb,
                                                  const int* __restrict__ y,
                                                  float* __restrict__ pS,
                                                  float* __restrict__ pT,
                                                  int* __restrict__ bar)
{
    const int rowblk = blockIdx.x;
    const int split  = blockIdx.y;
    const int t = threadIdx.x;
    const int wave = t >> 6, lane = t & 63;
    const int kg = lane >> 4, nl = lane & 15;
    const int is64 = bar[136];

    __shared__ float psum_l[4][64];
    __shared__ float ptarg_l[4][64];
    __shared__ float chk[1];

    bf16x8 afr[4][8];
    #pragma unroll
    for (int mt = 0; mt < 4; ++mt)
        #pragma unroll
        for (int kk = 0; kk < 8; ++kk)
            afr[mt][kk] = *(const bf16x8*)&zsb[(size_t)(rowblk*64 + mt*16 + nl) * EE + kk*32 + kg*8];

    int tg[4][4];
    #pragma unroll
    for (int mt = 0; mt < 4; ++mt)
        #pragma unroll
        for (int i = 0; i < 4; ++i){
            int rg = rowblk*64 + mt*16 + kg*4 + i;
            tg[mt][i] = is64 ? y[2*rg] : y[rg];
        }

    float sums[4][4]; float targ[4][4];
    #pragma unroll
    for (int mt = 0; mt < 4; ++mt)
        #pragma unroll
        for (int i = 0; i < 4; ++i){ sums[mt][i] = 0.f; targ[mt][i] = 0.f; }

    for (int tile = wave; tile < 500; tile += 4){
        int n = split*8000 + tile*16 + nl;
        f32x4 acc[4];
        #pragma unroll
        for (int mt = 0; mt < 4; ++mt) acc[mt] = (f32x4){0.f,0.f,0.f,0.f};
        #pragma unroll
        for (int kk = 0; kk < 8; ++kk){
            bf16x8 bfr;
            if (VB) bfr = *(const bf16x8*)&vb[(size_t)n * EE + kk*32 + kg*8];
            else    bfr = pack8f(&vwf[(size_t)n * EE + kk*32 + kg*8]);
            #pragma unroll
            for (int mt = 0; mt < 4; ++mt)
                acc[mt] = __builtin_amdgcn_mfma_f32_16x16x32_bf16(afr[mt][kk], bfr, acc[mt], 0, 0, 0);
        }
        float bias = vbias[n];
        if (rowblk == 0 && split == 0 && t == 0 && tile == 0)
            chk[0] = acc[0][0] + bias;
        #pragma unroll
        for (int mt = 0; mt < 4; ++mt)
            #pragma unroll
            for (int i = 0; i < 4; ++i){
                float v = acc[mt][i] + bias;
                sums[mt][i] += expf(v);
                if (n == tg[mt][i]) targ[mt][i] += v;
            }
    }

    #pragma unroll
    for (int mt = 0; mt < 4; ++mt)
        #pragma unroll
        for (int i = 0; i < 4; ++i){
            float sv = sums[mt][i], tv = targ[mt][i];
            #pragma unroll
            for (int msk = 1; msk < 16; msk <<= 1){ sv += __shfl_xor(sv, msk); tv += __shfl_xor(tv, msk); }
            if (nl == 0){ int row = mt*16 + kg*4 + i; psum_l[wave][row] = sv; ptarg_l[wave][row] = tv; }
        }
    __syncthreads();
    if (t < 64){
        float sv = psum_l[0][t] + psum_l[1][t] + psum_l[2][t] + psum_l[3][t];
        float tv = ptarg_l[0][t] + ptarg_l[1][t] + ptarg_l[2][t] + ptarg_l[3][t];
        int r = rowblk*64 + t;
        pS[(size_t)split*ROWS + r] = sv;
        pT[(size_t)split*ROWS + r] = tv;
    }

    if (rowblk == 0 && split == 0 && t == 0){
        float s = 0.f;
        for (int k = 0; k < EE; ++k){
            float a = bf2f(zsb[k]);
            float w = VB ? bf2f(vb[k]) : bf2f(f2bf_bits(vwf[k]));
            s += a * w;
        }
        s += vbias[0];
        if (fabsf(s - chk[0]) > 0.02f) bar[133] = 1;
    }
}

__global__ __launch_bounds__(256) void k_final(const float* __restrict__ pS,
                                               const float* __restrict__ pT,
                                               const int* __restrict__ bar,
                                               float* __restrict__ outp)
{
    int r = blockIdx.x * 256 + threadIdx.x;
    float s = 0.f, g = 0.f;
    #pragma unroll
    for (int i = 0; i < VSPLIT; ++i){ s += pS[(size_t)i*ROWS + r]; g += pT[(size_t)i*ROWS + r]; }
    float v = g - logf(s);
    if (bar[132] != 0) v = 4000.0f;    // pipeline timeout sentinel
    if (bar[133] != 0) v = 5000.0f;    // MFMA layout mismatch sentinel
    outp[r] = v;
}

extern "C" void kernel_launch(void* const* d_in, const int* in_sizes, int n_in,
                              void* d_out, int out_size, void* d_ws, size_t ws_size,
                              hipStream_t stream)
{
    (void)out_size;
    const float* latent   = (const float*)d_in[0];
    const float* trans_w  = (const float*)d_in[1];
    const float* trans_b  = (const float*)d_in[2];
    const float* anchor_w = (const float*)d_in[3];
    const float* anchor_b = (const float*)d_in[4];
    const float* vocab_w  = (const float*)d_in[5];
    const float* vocab_b  = (const float*)d_in[6];
    const int*   zi       = (const int*)d_in[7];
    const int*   y        = (const int*)d_in[8];

    float* outp = (float*)d_out;

    if (ws_size < (size_t)WS_REQ){ k_sentinel<<<16, 256, 0, stream>>>(outp, 2000.0f); return; }
    {
        bool ok = (n_in >= 9)
               && in_sizes[0] == 67108864 && in_sizes[1] == 1048576
               && in_sizes[2] == 4096     && in_sizes[3] == 4096
               && in_sizes[4] == 16       && in_sizes[5] == 8192000
               && in_sizes[6] == 32000
               && (in_sizes[7] == 32   || in_sizes[7] == 64)
               && (in_sizes[8] == 4096 || in_sizes[8] == 8192);
        if (!ok){ k_sentinel<<<16, 256, 0, stream>>>(outp, 2100.0f); return; }
    }

    char* ws = (char*)d_ws;
    unsigned short* zsb = (unsigned short*)(ws + OFF_ZSB);
    float*    pS  = (float*)(ws + OFF_PS);
    float*    pT  = (float*)(ws + OFF_PT);
    unsigned* ZNB = (unsigned*)(ws + OFF_ZNB);
    int*      bar = (int*)(ws + OFF_BAR);
    float*    PD  = (float*)(ws + OFF_PD);
    unsigned short* vbu = (unsigned short*)(ws + OFF_VB);

    const bool use_vb = ws_size >= (size_t)OFF_VB + (size_t)VB_BYTES;

    k_prep<<<1, 256, 0, stream>>>(zi, bar);
    if (use_vb)
        k_cvt<<<GG*EE/1024, 256, 0, stream>>>(vocab_w, vbu);

    k_rnn<<<NWGR, 512, 0, stream>>>(latent, zi, anchor_w, anchor_b,
                                    trans_w, trans_b, zsb, ZNB, PD, bar);

    if (use_vb)
        k_vocab<true><<<dim3(64, VSPLIT), 256, 0, stream>>>(vbu, nullptr, vocab_b,
                                                            zsb, y, pS, pT, bar);
    else
        k_vocab<false><<<dim3(64, VSPLIT), 256, 0, stream>>>(nullptr, vocab_w, vocab_b,
                                                             zsb, y, pS, pT, bar);

    k_final<<<16, 256, 0, stream>>>(pS, pT, bar, outp);
}